// Round 1
// baseline (1532.687 us; speedup 1.0000x reference)
//
#include <hip/hip_runtime.h>

#define N_NODES 100000
#define N_EDGES 600000
#define HID 128
#define OUT_DIM 256
#define N_GRAPHS 256
#define NPB 8      // nodes per block in SAGE gemm kernel
#define CHUNK 16   // nodes per block in pool kernel

// ---------------- degree count (once) ----------------
__global__ void count_kernel(const int* __restrict__ dst, float* __restrict__ cnt) {
    int e = blockIdx.x * blockDim.x + threadIdx.x;
    if (e < N_EDGES) atomicAdd(&cnt[dst[e]], 1.0f);
}

// ---------------- scatter-add neighbor features ----------------
__global__ __launch_bounds__(256) void scatter_kernel(
    const int* __restrict__ src, const int* __restrict__ dst,
    const float* __restrict__ h, float* __restrict__ agg)
{
    int gid = blockIdx.x * 256 + threadIdx.x;   // 76.8M threads total
    int e = gid >> 7;
    int d = gid & 127;
    if (e < N_EDGES) {
        int s = src[e];
        int t = dst[e];
        atomicAdd(&agg[(long long)t * HID + d], h[(long long)s * HID + d]);
    }
}

// ---------------- fused SAGE linear + LayerNorm + ReLU ----------------
__global__ __launch_bounds__(128) void sage_kernel(
    const float* __restrict__ h_in, const float* __restrict__ agg,
    const float* __restrict__ cnt,
    const float* __restrict__ Wl, const float* __restrict__ Wr,
    const float* __restrict__ bias,
    const float* __restrict__ gamma, const float* __restrict__ beta,
    float* __restrict__ h_out)
{
    __shared__ float sm_mean[NPB][HID];
    __shared__ float sm_h[NPB][HID];
    __shared__ float red[2][2];

    int tid = threadIdx.x;
    int node0 = blockIdx.x * NPB;

    #pragma unroll
    for (int n = 0; n < NPB; ++n) {
        int node = node0 + n;
        float inv = 1.0f / fmaxf(cnt[node], 1.0f);
        sm_mean[n][tid] = agg[(long long)node * HID + tid] * inv;
        sm_h[n][tid]    = h_in[(long long)node * HID + tid];
    }
    __syncthreads();

    float acc[NPB];
    float b0 = bias[tid];
    #pragma unroll
    for (int n = 0; n < NPB; ++n) acc[n] = b0;

    for (int k = 0; k < HID; ++k) {
        float wl = Wl[k * HID + tid];
        float wr = Wr[k * HID + tid];
        #pragma unroll
        for (int n = 0; n < NPB; ++n)
            acc[n] += sm_mean[n][k] * wl + sm_h[n][k] * wr;
    }

    float gm = gamma[tid], bt = beta[tid];
    int wv = tid >> 6, lane = tid & 63;

    for (int n = 0; n < NPB; ++n) {
        float v = acc[n];
        float s = v, ss = v * v;
        #pragma unroll
        for (int off = 32; off >= 1; off >>= 1) {
            s  += __shfl_xor(s,  off, 64);
            ss += __shfl_xor(ss, off, 64);
        }
        __syncthreads();
        if (lane == 0) { red[wv][0] = s; red[wv][1] = ss; }
        __syncthreads();
        float tot  = red[0][0] + red[1][0];
        float tots = red[0][1] + red[1][1];
        float mu  = tot  * (1.0f / HID);
        float var = tots * (1.0f / HID) - mu * mu;
        float rs = rsqrtf(var + 1e-5f);
        float o = (v - mu) * rs * gm + bt;
        h_out[(long long)(node0 + n) * HID + tid] = fmaxf(o, 0.0f);
    }
}

// ---------------- per-graph mean/max pool (graph_batch is sorted) ----------------
__global__ __launch_bounds__(128) void pool_kernel(
    const float* __restrict__ h, const int* __restrict__ gb,
    float* __restrict__ gsum, float* __restrict__ gmax, float* __restrict__ gcnt)
{
    int tid = threadIdx.x;
    int start = blockIdx.x * CHUNK;
    if (start >= N_NODES) return;
    int end = min(start + CHUNK, N_NODES);

    int curg = gb[start];
    float s = 0.f, m = 0.f;
    int c = 0;
    for (int node = start; node < end; ++node) {
        int g = gb[node];
        if (g != curg) {
            atomicAdd(&gsum[curg * HID + tid], s);
            atomicMax((int*)&gmax[curg * HID + tid], __float_as_int(m));
            if (tid == 0) atomicAdd(&gcnt[curg], (float)c);
            curg = g; s = 0.f; m = 0.f; c = 0;
        }
        float v = h[(long long)node * HID + tid];
        s += v;
        m = fmaxf(m, v);   // post-ReLU: v >= 0, init 0 is safe
        ++c;
    }
    atomicAdd(&gsum[curg * HID + tid], s);
    atomicMax((int*)&gmax[curg * HID + tid], __float_as_int(m));
    if (tid == 0) atomicAdd(&gcnt[curg], (float)c);
}

// ---------------- readout MLP + L2 normalize ----------------
__global__ __launch_bounds__(256) void readout_kernel(
    const float* __restrict__ gsum, const float* __restrict__ gmax,
    const float* __restrict__ gcnt,
    const float* __restrict__ Wr1, const float* __restrict__ br1,
    const float* __restrict__ Wr2, const float* __restrict__ br2,
    float* __restrict__ out)
{
    __shared__ float pooled[2 * HID];
    __shared__ float hid[HID];
    __shared__ float red[4];

    int g = blockIdx.x, tid = threadIdx.x;

    if (tid < HID) {
        float n = fmaxf(gcnt[g], 1.0f);
        pooled[tid] = gsum[g * HID + tid] / n;
    } else {
        pooled[tid] = gmax[g * HID + (tid - HID)];
    }
    __syncthreads();

    if (tid < HID) {
        float a = br1[tid];
        for (int k = 0; k < 2 * HID; ++k)
            a += pooled[k] * Wr1[k * HID + tid];
        hid[tid] = fmaxf(a, 0.0f);
    }
    __syncthreads();

    float a = br2[tid];
    for (int k = 0; k < HID; ++k)
        a += hid[k] * Wr2[k * OUT_DIM + tid];

    float ss = a * a;
    #pragma unroll
    for (int off = 32; off >= 1; off >>= 1) ss += __shfl_xor(ss, off, 64);
    int wv = tid >> 6, lane = tid & 63;
    if (lane == 0) red[wv] = ss;
    __syncthreads();
    float tot = red[0] + red[1] + red[2] + red[3];
    float nrm = fmaxf(sqrtf(tot), 1e-12f);
    out[g * OUT_DIM + tid] = a / nrm;
}

extern "C" void kernel_launch(void* const* d_in, const int* in_sizes, int n_in,
                              void* d_out, int out_size, void* d_ws, size_t ws_size,
                              hipStream_t stream) {
    const float* x   = (const float*)d_in[0];
    const int*   ei  = (const int*)d_in[1];     // [2, N_EDGES]: src then dst
    const int*   gb  = (const int*)d_in[2];
    const float* W1l = (const float*)d_in[3];
    const float* W1r = (const float*)d_in[4];
    const float* b1  = (const float*)d_in[5];
    const float* g1  = (const float*)d_in[6];
    const float* be1 = (const float*)d_in[7];
    const float* W2l = (const float*)d_in[8];
    const float* W2r = (const float*)d_in[9];
    const float* b2  = (const float*)d_in[10];
    const float* g2  = (const float*)d_in[11];
    const float* be2 = (const float*)d_in[12];
    const float* W3l = (const float*)d_in[13];
    const float* W3r = (const float*)d_in[14];
    const float* b3  = (const float*)d_in[15];
    const float* g3  = (const float*)d_in[16];
    const float* be3 = (const float*)d_in[17];
    const float* Wr1 = (const float*)d_in[18];
    const float* br1 = (const float*)d_in[19];
    const float* Wr2 = (const float*)d_in[20];
    const float* br2 = (const float*)d_in[21];

    const int* src = ei;
    const int* dst = ei + N_EDGES;

    char* ws = (char*)d_ws;
    size_t off = 0;
    auto alloc = [&](size_t bytes) -> void* {
        void* p = ws + off;
        off += (bytes + 255) & ~(size_t)255;
        return p;
    };
    float* agg  = (float*)alloc((size_t)N_NODES * HID * 4);
    float* hA   = (float*)alloc((size_t)N_NODES * HID * 4);
    float* hB   = (float*)alloc((size_t)N_NODES * HID * 4);
    float* cnt  = (float*)alloc((size_t)N_NODES * 4);
    float* gsum = (float*)alloc((size_t)N_GRAPHS * HID * 4);
    float* gmax = (float*)alloc((size_t)N_GRAPHS * HID * 4);
    float* gcnt = (float*)alloc((size_t)N_GRAPHS * 4);

    const int scatter_blocks = (N_EDGES * (HID / 256)) + 0;  // 600000*128/256
    (void)scatter_blocks;

    // degree counts (constant across layers)
    hipMemsetAsync(cnt, 0, (size_t)N_NODES * 4, stream);
    count_kernel<<<(N_EDGES + 255) / 256, 256, 0, stream>>>(dst, cnt);

    // ---- layer 1: in = x, out = hA ----
    hipMemsetAsync(agg, 0, (size_t)N_NODES * HID * 4, stream);
    scatter_kernel<<<(N_EDGES * HID) / 256, 256, 0, stream>>>(src, dst, x, agg);
    sage_kernel<<<N_NODES / NPB, 128, 0, stream>>>(x, agg, cnt, W1l, W1r, b1, g1, be1, hA);

    // ---- layer 2: in = hA, out = hB ----
    hipMemsetAsync(agg, 0, (size_t)N_NODES * HID * 4, stream);
    scatter_kernel<<<(N_EDGES * HID) / 256, 256, 0, stream>>>(src, dst, hA, agg);
    sage_kernel<<<N_NODES / NPB, 128, 0, stream>>>(hA, agg, cnt, W2l, W2r, b2, g2, be2, hB);

    // ---- layer 3: in = hB, out = hA ----
    hipMemsetAsync(agg, 0, (size_t)N_NODES * HID * 4, stream);
    scatter_kernel<<<(N_EDGES * HID) / 256, 256, 0, stream>>>(src, dst, hB, agg);
    sage_kernel<<<N_NODES / NPB, 128, 0, stream>>>(hB, agg, cnt, W3l, W3r, b3, g3, be3, hA);

    // ---- pooling ----
    hipMemsetAsync(gsum, 0, (size_t)N_GRAPHS * HID * 4, stream);
    hipMemsetAsync(gmax, 0, (size_t)N_GRAPHS * HID * 4, stream);
    hipMemsetAsync(gcnt, 0, (size_t)N_GRAPHS * 4, stream);
    pool_kernel<<<(N_NODES + CHUNK - 1) / CHUNK, 128, 0, stream>>>(hA, gb, gsum, gmax, gcnt);

    // ---- readout ----
    readout_kernel<<<N_GRAPHS, 256, 0, stream>>>(gsum, gmax, gcnt, Wr1, br1, Wr2, br2, (float*)d_out);
}

// Round 2
// 1095.468 us; speedup vs baseline: 1.3991x; 1.3991x over previous
//
#include <hip/hip_runtime.h>

#define N_NODES 100000
#define N_EDGES 600000
#define HID 128
#define OUT_DIM 256
#define N_GRAPHS 256
#define BN 32          // nodes per block in fused SAGE kernel
#define LDP (HID + 4)  // padded LDS row stride (floats) — breaks bank alignment
#define CHUNK 16       // nodes per block in pool kernel
#define SCAN_B 512
#define SCAN_NB ((N_NODES + SCAN_B) / SCAN_B)   // 196 blocks covers 0..N_NODES inclusive

// ---------------- degree count (int) ----------------
__global__ void count_kernel(const int* __restrict__ dst, int* __restrict__ deg) {
    int e = blockIdx.x * blockDim.x + threadIdx.x;
    if (e < N_EDGES) atomicAdd(&deg[dst[e]], 1);
}

// ---------------- block-level exclusive scan ----------------
__global__ __launch_bounds__(SCAN_B) void scan1_kernel(
    const int* __restrict__ deg, int* __restrict__ part, int* __restrict__ bsum)
{
    __shared__ int s[SCAN_B];
    int t = threadIdx.x;
    int i = blockIdx.x * SCAN_B + t;
    int v = (i < N_NODES) ? deg[i] : 0;
    s[t] = v;
    __syncthreads();
    #pragma unroll
    for (int off = 1; off < SCAN_B; off <<= 1) {
        int x = (t >= off) ? s[t - off] : 0;
        __syncthreads();
        s[t] += x;
        __syncthreads();
    }
    part[i] = s[t] - v;               // exclusive
    if (t == SCAN_B - 1) bsum[blockIdx.x] = s[t];
}

// ---------------- scan of block sums (single block) ----------------
__global__ __launch_bounds__(256) void scan2_kernel(
    const int* __restrict__ bsum, int* __restrict__ boff)
{
    __shared__ int s[256];
    int t = threadIdx.x;
    int v = (t < SCAN_NB) ? bsum[t] : 0;
    s[t] = v;
    __syncthreads();
    #pragma unroll
    for (int off = 1; off < 256; off <<= 1) {
        int x = (t >= off) ? s[t - off] : 0;
        __syncthreads();
        s[t] += x;
        __syncthreads();
    }
    if (t < SCAN_NB) boff[t] = s[t] - v;   // exclusive
}

// ---------------- finalize row_ptr, cursor, invdeg ----------------
__global__ __launch_bounds__(SCAN_B) void scan3_kernel(
    const int* __restrict__ part, const int* __restrict__ boff,
    const int* __restrict__ deg,
    int* __restrict__ row_ptr, int* __restrict__ cursor, float* __restrict__ invdeg)
{
    int i = blockIdx.x * SCAN_B + threadIdx.x;
    int rp = part[i] + boff[blockIdx.x];
    if (i <= N_NODES) row_ptr[i] = rp;
    if (i < N_NODES) {
        cursor[i] = rp;
        invdeg[i] = 1.0f / (float)max(deg[i], 1);
    }
}

// ---------------- CSR fill ----------------
__global__ void fill_kernel(const int* __restrict__ src, const int* __restrict__ dst,
                            int* __restrict__ cursor, int* __restrict__ csr_src)
{
    int e = blockIdx.x * blockDim.x + threadIdx.x;
    if (e < N_EDGES) {
        int t = dst[e];
        int pos = atomicAdd(&cursor[t], 1);
        csr_src[pos] = src[e];
    }
}

// ---------------- fused gather + SAGE linear + LayerNorm + ReLU ----------------
__global__ __launch_bounds__(256) void sage_fused(
    const float* __restrict__ h_in,
    const int* __restrict__ row_ptr, const int* __restrict__ csr_src,
    const float* __restrict__ invdeg,
    const float* __restrict__ Wl, const float* __restrict__ Wr,
    const float* __restrict__ bias,
    const float* __restrict__ gamma, const float* __restrict__ beta,
    float* __restrict__ h_out)
{
    __shared__ float smA[BN][LDP];   // mean-aggregated neighbor features
    __shared__ float smH[BN][LDP];   // root features

    int tid = threadIdx.x;
    int node0 = blockIdx.x * BN;

    // -- stage root features (float4, coalesced) --
    for (int i = tid; i < BN * (HID / 4); i += 256) {
        int n = i >> 5;            // / (HID/4)
        int c = i & 31;            // % (HID/4)
        float4 v = ((const float4*)(h_in + (size_t)(node0 + n) * HID))[c];
        *(float4*)&smH[n][c * 4] = v;
    }

    // -- pull-gather neighbor mean: d = tid&127, node-sub = tid>>7 (wave-uniform) --
    {
        int d = tid & 127;
        for (int n = tid >> 7; n < BN; n += 2) {
            int node = node0 + n;
            int r0 = row_ptr[node], r1 = row_ptr[node + 1];
            float m = 0.f;
            for (int e = r0; e < r1; ++e) {
                int s = csr_src[e];                      // wave-uniform -> s_load
                m += h_in[(size_t)s * HID + d];
            }
            smA[n][d] = m * invdeg[node];
        }
    }
    __syncthreads();

    // -- GEMM: thread computes 4 nodes x 4 dims, float4-vectorized over k --
    int dgrp = tid & 31, ngrp = tid >> 5;
    int d0 = dgrp * 4, n0 = ngrp * 4;

    float acc[4][4];
    {
        float4 bv = *(const float4*)&bias[d0];
        #pragma unroll
        for (int n = 0; n < 4; ++n) {
            acc[n][0] = bv.x; acc[n][1] = bv.y; acc[n][2] = bv.z; acc[n][3] = bv.w;
        }
    }

    for (int k = 0; k < HID; k += 4) {
        float4 a[4], h[4], wl[4], wr[4];
        #pragma unroll
        for (int n = 0; n < 4; ++n) {
            a[n] = *(const float4*)&smA[n0 + n][k];
            h[n] = *(const float4*)&smH[n0 + n][k];
        }
        #pragma unroll
        for (int j = 0; j < 4; ++j) {
            wl[j] = *(const float4*)&Wl[(size_t)(k + j) * HID + d0];
            wr[j] = *(const float4*)&Wr[(size_t)(k + j) * HID + d0];
        }
        #pragma unroll
        for (int n = 0; n < 4; ++n) {
            const float* an = (const float*)&a[n];
            const float* hn = (const float*)&h[n];
            #pragma unroll
            for (int j = 0; j < 4; ++j) {
                acc[n][0] += an[j] * ((const float*)&wl[j])[0] + hn[j] * ((const float*)&wr[j])[0];
                acc[n][1] += an[j] * ((const float*)&wl[j])[1] + hn[j] * ((const float*)&wr[j])[1];
                acc[n][2] += an[j] * ((const float*)&wl[j])[2] + hn[j] * ((const float*)&wr[j])[2];
                acc[n][3] += an[j] * ((const float*)&wl[j])[3] + hn[j] * ((const float*)&wr[j])[3];
            }
        }
    }

    // -- LayerNorm + ReLU + store --
    // Within a wave, node row n lives on a 32-lane half (lanes share ngrp).
    float4 gm = *(const float4*)&gamma[d0];
    float4 bt = *(const float4*)&beta[d0];
    #pragma unroll
    for (int n = 0; n < 4; ++n) {
        float p = acc[n][0] + acc[n][1] + acc[n][2] + acc[n][3];
        float q = acc[n][0]*acc[n][0] + acc[n][1]*acc[n][1]
                + acc[n][2]*acc[n][2] + acc[n][3]*acc[n][3];
        #pragma unroll
        for (int off = 16; off >= 1; off >>= 1) {
            p += __shfl_xor(p, off, 64);
            q += __shfl_xor(q, off, 64);
        }
        float mu = p * (1.0f / HID);
        float var = q * (1.0f / HID) - mu * mu;
        float rs = rsqrtf(var + 1e-5f);
        float4 o;
        o.x = fmaxf((acc[n][0] - mu) * rs * gm.x + bt.x, 0.f);
        o.y = fmaxf((acc[n][1] - mu) * rs * gm.y + bt.y, 0.f);
        o.z = fmaxf((acc[n][2] - mu) * rs * gm.z + bt.z, 0.f);
        o.w = fmaxf((acc[n][3] - mu) * rs * gm.w + bt.w, 0.f);
        *(float4*)&h_out[(size_t)(node0 + n0 + n) * HID + d0] = o;
    }
}

// ---------------- per-graph mean/max pool (graph_batch is sorted) ----------------
__global__ __launch_bounds__(128) void pool_kernel(
    const float* __restrict__ h, const int* __restrict__ gb,
    float* __restrict__ gsum, float* __restrict__ gmax, float* __restrict__ gcnt)
{
    int tid = threadIdx.x;
    int start = blockIdx.x * CHUNK;
    if (start >= N_NODES) return;
    int end = min(start + CHUNK, N_NODES);

    int curg = gb[start];
    float s = 0.f, m = 0.f;
    int c = 0;
    for (int node = start; node < end; ++node) {
        int g = gb[node];
        if (g != curg) {
            atomicAdd(&gsum[curg * HID + tid], s);
            atomicMax((int*)&gmax[curg * HID + tid], __float_as_int(m));
            if (tid == 0) atomicAdd(&gcnt[curg], (float)c);
            curg = g; s = 0.f; m = 0.f; c = 0;
        }
        float v = h[(size_t)node * HID + tid];
        s += v;
        m = fmaxf(m, v);   // post-ReLU: v >= 0, init 0 is safe
        ++c;
    }
    atomicAdd(&gsum[curg * HID + tid], s);
    atomicMax((int*)&gmax[curg * HID + tid], __float_as_int(m));
    if (tid == 0) atomicAdd(&gcnt[curg], (float)c);
}

// ---------------- readout MLP + L2 normalize ----------------
__global__ __launch_bounds__(256) void readout_kernel(
    const float* __restrict__ gsum, const float* __restrict__ gmax,
    const float* __restrict__ gcnt,
    const float* __restrict__ Wr1, const float* __restrict__ br1,
    const float* __restrict__ Wr2, const float* __restrict__ br2,
    float* __restrict__ out)
{
    __shared__ float pooled[2 * HID];
    __shared__ float hid[HID];
    __shared__ float red[4];

    int g = blockIdx.x, tid = threadIdx.x;

    if (tid < HID) {
        float n = fmaxf(gcnt[g], 1.0f);
        pooled[tid] = gsum[g * HID + tid] / n;
    } else {
        pooled[tid] = gmax[g * HID + (tid - HID)];
    }
    __syncthreads();

    if (tid < HID) {
        float a = br1[tid];
        for (int k = 0; k < 2 * HID; ++k)
            a += pooled[k] * Wr1[k * HID + tid];
        hid[tid] = fmaxf(a, 0.0f);
    }
    __syncthreads();

    float a = br2[tid];
    for (int k = 0; k < HID; ++k)
        a += hid[k] * Wr2[k * OUT_DIM + tid];

    float ss = a * a;
    #pragma unroll
    for (int off = 32; off >= 1; off >>= 1) ss += __shfl_xor(ss, off, 64);
    int wv = tid >> 6, lane = tid & 63;
    if (lane == 0) red[wv] = ss;
    __syncthreads();
    float tot = red[0] + red[1] + red[2] + red[3];
    float nrm = fmaxf(sqrtf(tot), 1e-12f);
    out[g * OUT_DIM + tid] = a / nrm;
}

extern "C" void kernel_launch(void* const* d_in, const int* in_sizes, int n_in,
                              void* d_out, int out_size, void* d_ws, size_t ws_size,
                              hipStream_t stream) {
    const float* x   = (const float*)d_in[0];
    const int*   ei  = (const int*)d_in[1];     // [2, N_EDGES]: src then dst
    const int*   gb  = (const int*)d_in[2];
    const float* W1l = (const float*)d_in[3];
    const float* W1r = (const float*)d_in[4];
    const float* b1  = (const float*)d_in[5];
    const float* g1  = (const float*)d_in[6];
    const float* be1 = (const float*)d_in[7];
    const float* W2l = (const float*)d_in[8];
    const float* W2r = (const float*)d_in[9];
    const float* b2  = (const float*)d_in[10];
    const float* g2  = (const float*)d_in[11];
    const float* be2 = (const float*)d_in[12];
    const float* W3l = (const float*)d_in[13];
    const float* W3r = (const float*)d_in[14];
    const float* b3  = (const float*)d_in[15];
    const float* g3  = (const float*)d_in[16];
    const float* be3 = (const float*)d_in[17];
    const float* Wr1 = (const float*)d_in[18];
    const float* br1 = (const float*)d_in[19];
    const float* Wr2 = (const float*)d_in[20];
    const float* br2 = (const float*)d_in[21];

    const int* src = ei;
    const int* dst = ei + N_EDGES;

    char* ws = (char*)d_ws;
    size_t off = 0;
    auto alloc = [&](size_t bytes) -> void* {
        void* p = ws + off;
        off += (bytes + 255) & ~(size_t)255;
        return p;
    };
    float* hA      = (float*)alloc((size_t)N_NODES * HID * 4);
    float* hB      = (float*)alloc((size_t)N_NODES * HID * 4);
    int*   deg     = (int*)alloc((size_t)N_NODES * 4);
    int*   part    = (int*)alloc((size_t)SCAN_NB * SCAN_B * 4);
    int*   bsum    = (int*)alloc((size_t)SCAN_NB * 4);
    int*   boff    = (int*)alloc((size_t)SCAN_NB * 4);
    int*   row_ptr = (int*)alloc((size_t)(N_NODES + 1) * 4);
    int*   cursor  = (int*)alloc((size_t)N_NODES * 4);
    float* invdeg  = (float*)alloc((size_t)N_NODES * 4);
    int*   csr_src = (int*)alloc((size_t)N_EDGES * 4);
    float* gsum    = (float*)alloc((size_t)N_GRAPHS * HID * 4);
    float* gmax    = (float*)alloc((size_t)N_GRAPHS * HID * 4);
    float* gcnt    = (float*)alloc((size_t)N_GRAPHS * 4);

    // ---- build CSR (once, reused by all 3 layers) ----
    hipMemsetAsync(deg, 0, (size_t)N_NODES * 4, stream);
    count_kernel<<<(N_EDGES + 255) / 256, 256, 0, stream>>>(dst, deg);
    scan1_kernel<<<SCAN_NB, SCAN_B, 0, stream>>>(deg, part, bsum);
    scan2_kernel<<<1, 256, 0, stream>>>(bsum, boff);
    scan3_kernel<<<SCAN_NB, SCAN_B, 0, stream>>>(part, boff, deg, row_ptr, cursor, invdeg);
    fill_kernel<<<(N_EDGES + 255) / 256, 256, 0, stream>>>(src, dst, cursor, csr_src);

    const int sage_blocks = N_NODES / BN;   // 3125, exact

    // ---- 3 fused SAGE layers ----
    sage_fused<<<sage_blocks, 256, 0, stream>>>(x,  row_ptr, csr_src, invdeg, W1l, W1r, b1, g1, be1, hA);
    sage_fused<<<sage_blocks, 256, 0, stream>>>(hA, row_ptr, csr_src, invdeg, W2l, W2r, b2, g2, be2, hB);
    sage_fused<<<sage_blocks, 256, 0, stream>>>(hB, row_ptr, csr_src, invdeg, W3l, W3r, b3, g3, be3, hA);

    // ---- pooling ----
    hipMemsetAsync(gsum, 0, (size_t)N_GRAPHS * HID * 4, stream);
    hipMemsetAsync(gmax, 0, (size_t)N_GRAPHS * HID * 4, stream);
    hipMemsetAsync(gcnt, 0, (size_t)N_GRAPHS * 4, stream);
    pool_kernel<<<(N_NODES + CHUNK - 1) / CHUNK, 128, 0, stream>>>(hA, gb, gsum, gmax, gcnt);

    // ---- readout ----
    readout_kernel<<<N_GRAPHS, 256, 0, stream>>>(gsum, gmax, gcnt, Wr1, br1, Wr2, br2, (float*)d_out);
}

// Round 3
// 660.248 us; speedup vs baseline: 2.3214x; 1.6592x over previous
//
#include <hip/hip_runtime.h>
#include <hip/hip_bf16.h>

#define N_NODES 100000
#define N_EDGES 600000
#define HID 128
#define OUT_DIM 256
#define N_GRAPHS 256
#define BN 64            // nodes per block in fused SAGE kernel
#define K2 256           // stacked K (agg | root)
#define LDA 260          // smA row stride in floats: 260*4B/16B = 65 (odd) -> conflict-free b128
#define CHUNK 16
#define SCAN_B 512
#define SCAN_NB ((N_NODES + SCAN_B) / SCAN_B)

typedef __attribute__((ext_vector_type(8))) __bf16 bf16x8;
typedef __attribute__((ext_vector_type(4))) float f32x4;

__device__ inline f32x4 mfma16(bf16x8 a, bf16x8 b, f32x4 c) {
    return __builtin_amdgcn_mfma_f32_16x16x32_bf16(a, b, c, 0, 0, 0);
}

__device__ inline unsigned short bf_bits(__bf16 b) {
    union { __bf16 b; unsigned short u; } x; x.b = b; return x.u;
}

// ---------------- degree count ----------------
__global__ void count_kernel(const int* __restrict__ dst, int* __restrict__ deg) {
    int e = blockIdx.x * blockDim.x + threadIdx.x;
    if (e < N_EDGES) atomicAdd(&deg[dst[e]], 1);
}

// ---------------- block-level exclusive scan ----------------
__global__ __launch_bounds__(SCAN_B) void scan1_kernel(
    const int* __restrict__ deg, int* __restrict__ part, int* __restrict__ bsum)
{
    __shared__ int s[SCAN_B];
    int t = threadIdx.x;
    int i = blockIdx.x * SCAN_B + t;
    int v = (i < N_NODES) ? deg[i] : 0;
    s[t] = v;
    __syncthreads();
    #pragma unroll
    for (int off = 1; off < SCAN_B; off <<= 1) {
        int x = (t >= off) ? s[t - off] : 0;
        __syncthreads();
        s[t] += x;
        __syncthreads();
    }
    part[i] = s[t] - v;
    if (t == SCAN_B - 1) bsum[blockIdx.x] = s[t];
}

__global__ __launch_bounds__(256) void scan2_kernel(
    const int* __restrict__ bsum, int* __restrict__ boff)
{
    __shared__ int s[256];
    int t = threadIdx.x;
    int v = (t < SCAN_NB) ? bsum[t] : 0;
    s[t] = v;
    __syncthreads();
    #pragma unroll
    for (int off = 1; off < 256; off <<= 1) {
        int x = (t >= off) ? s[t - off] : 0;
        __syncthreads();
        s[t] += x;
        __syncthreads();
    }
    if (t < SCAN_NB) boff[t] = s[t] - v;
}

__global__ __launch_bounds__(SCAN_B) void scan3_kernel(
    const int* __restrict__ part, const int* __restrict__ boff,
    const int* __restrict__ deg,
    int* __restrict__ row_ptr, int* __restrict__ cursor, float* __restrict__ invdeg)
{
    int i = blockIdx.x * SCAN_B + threadIdx.x;
    int rp = part[i] + boff[blockIdx.x];
    if (i <= N_NODES) row_ptr[i] = rp;
    if (i < N_NODES) {
        cursor[i] = rp;
        invdeg[i] = 1.0f / (float)max(deg[i], 1);
    }
}

__global__ void fill_kernel(const int* __restrict__ src, const int* __restrict__ dst,
                            int* __restrict__ cursor, int* __restrict__ csr_src)
{
    int e = blockIdx.x * blockDim.x + threadIdx.x;
    if (e < N_EDGES) {
        int t = dst[e];
        int pos = atomicAdd(&cursor[t], 1);
        csr_src[pos] = src[e];
    }
}

// ---------------- weight prep: stacked [Wl;Wr] -> fragment-major bf16 hi/lo ----------------
// layout (ushort): p*32768 + ks*4096 + nf*512 + lane*8 + j
//   value = W[k = ks*32 + (lane>>4)*8 + j][c = nf*16 + (lane&15)], p0=hi, p1=lo
__global__ __launch_bounds__(256) void prep_w(const float* __restrict__ Wl,
                                              const float* __restrict__ Wr,
                                              unsigned short* __restrict__ wf)
{
    int flat = blockIdx.x * 256 + threadIdx.x;   // 32768 total
    int j  = flat & 7;
    int l  = (flat >> 3) & 63;
    int nf = (flat >> 9) & 7;
    int ks = flat >> 12;
    int k = ks * 32 + ((l >> 4) << 3) + j;
    int c = nf * 16 + (l & 15);
    float v = (k < HID) ? Wl[k * HID + c] : Wr[(k - HID) * HID + c];
    __bf16 hi = (__bf16)v;
    __bf16 lo = (__bf16)(v - (float)hi);
    wf[flat]         = bf_bits(hi);
    wf[32768 + flat] = bf_bits(lo);
}

// ---------------- fused gather + split-bf16 MFMA GEMM + LayerNorm + ReLU ----------------
__global__ __launch_bounds__(256, 2) void sage_mfma(
    const float* __restrict__ h_in,
    const int* __restrict__ row_ptr, const int* __restrict__ csr_src,
    const float* __restrict__ invdeg,
    const unsigned short* __restrict__ wf,
    const float* __restrict__ bias, const float* __restrict__ gamma,
    const float* __restrict__ beta,
    float* __restrict__ h_out)
{
    __shared__ float smA[BN * LDA];          // 66560 B: [node][k], k0-127 agg, k128-255 root
    __shared__ float lnred[BN][4][2];        // 2 KB cross-wave LN partials

    const int tid  = threadIdx.x;
    const int lane = tid & 63;
    const int w    = tid >> 6;
    const int lq   = lane & 15;
    const int lg   = lane >> 4;
    const int node0 = blockIdx.x * BN;

    // ---- stage root h into smA[n][128..255] (coalesced float4) ----
    for (int i = tid; i < BN * 32; i += 256) {
        int n = i >> 5, c = (i & 31) * 4;
        int node = min(node0 + n, N_NODES - 1);
        float4 v = *(const float4*)(h_in + (size_t)node * HID + c);
        *(float4*)&smA[n * LDA + HID + c] = v;
    }

    // ---- gather neighbor mean into smA[n][0..127]: wave-per-stream, 4-deep unroll ----
    {
        const int d = lane * 2;
        for (int n = w * 16; n < w * 16 + 16; ++n) {
            int node = node0 + n;
            float mx = 0.f, my = 0.f;
            if (node < N_NODES) {
                int e = row_ptr[node], r1 = row_ptr[node + 1];
                float m1x = 0.f, m1y = 0.f, m2x = 0.f, m2y = 0.f, m3x = 0.f, m3y = 0.f;
                for (; e + 4 <= r1; e += 4) {
                    int s0 = csr_src[e], s1 = csr_src[e + 1], s2 = csr_src[e + 2], s3 = csr_src[e + 3];
                    float2 v0 = *(const float2*)(h_in + (size_t)s0 * HID + d);
                    float2 v1 = *(const float2*)(h_in + (size_t)s1 * HID + d);
                    float2 v2 = *(const float2*)(h_in + (size_t)s2 * HID + d);
                    float2 v3 = *(const float2*)(h_in + (size_t)s3 * HID + d);
                    mx  += v0.x; my  += v0.y;
                    m1x += v1.x; m1y += v1.y;
                    m2x += v2.x; m2y += v2.y;
                    m3x += v3.x; m3y += v3.y;
                }
                for (; e < r1; ++e) {
                    int s = csr_src[e];
                    float2 v = *(const float2*)(h_in + (size_t)s * HID + d);
                    mx += v.x; my += v.y;
                }
                float inv = invdeg[node];
                mx = (mx + m1x + m2x + m3x) * inv;
                my = (my + m1y + m2y + m3y) * inv;
            }
            float2 out2; out2.x = mx; out2.y = my;
            *(float2*)&smA[n * LDA + d] = out2;
        }
    }
    __syncthreads();

    // ---- split-bf16 MFMA GEMM: out[64 x 128] = A[64 x 256] @ W[256 x 128] ----
    const int nf0 = w * 2;
    const int col0 = nf0 * 16 + lq;          // = w*32 + lq
    const int col1 = col0 + 16;

    f32x4 acc[4][2];
    {
        float b0 = bias[col0], b1 = bias[col1];
        #pragma unroll
        for (int m = 0; m < 4; ++m) {
            acc[m][0] = (f32x4){b0, b0, b0, b0};
            acc[m][1] = (f32x4){b1, b1, b1, b1};
        }
    }

    const bf16x8* wfv = (const bf16x8*)wf;
    #pragma unroll 2
    for (int ks = 0; ks < 8; ++ks) {
        int base = (ks << 9) + nf0 * 64 + lane;      // ushort8 units
        bf16x8 bh0 = wfv[base];
        bf16x8 bh1 = wfv[base + 64];
        bf16x8 bl0 = wfv[base + 4096];
        bf16x8 bl1 = wfv[base + 4096 + 64];
        #pragma unroll
        for (int m = 0; m < 4; ++m) {
            const float* ap = &smA[(m * 16 + lq) * LDA + (ks << 5) + (lg << 3)];
            float4 a0 = *(const float4*)ap;
            float4 a1 = *(const float4*)(ap + 4);
            float av[8] = {a0.x, a0.y, a0.z, a0.w, a1.x, a1.y, a1.z, a1.w};
            bf16x8 ahi, alo;
            #pragma unroll
            for (int j = 0; j < 8; ++j) {
                __bf16 h = (__bf16)av[j];
                ahi[j] = h;
                alo[j] = (__bf16)(av[j] - (float)h);
            }
            acc[m][0] = mfma16(ahi, bh0, acc[m][0]);
            acc[m][0] = mfma16(alo, bh0, acc[m][0]);
            acc[m][0] = mfma16(ahi, bl0, acc[m][0]);
            acc[m][1] = mfma16(ahi, bh1, acc[m][1]);
            acc[m][1] = mfma16(alo, bh1, acc[m][1]);
            acc[m][1] = mfma16(ahi, bl1, acc[m][1]);
        }
    }

    // ---- LayerNorm partials: value (m, nf, r) sits at node m*16+lg*4+r, col col{nf} ----
    #pragma unroll
    for (int m = 0; m < 4; ++m) {
        #pragma unroll
        for (int r = 0; r < 4; ++r) {
            float pv = acc[m][0][r] + acc[m][1][r];
            float qv = acc[m][0][r] * acc[m][0][r] + acc[m][1][r] * acc[m][1][r];
            #pragma unroll
            for (int off = 8; off >= 1; off >>= 1) {
                pv += __shfl_xor(pv, off, 64);
                qv += __shfl_xor(qv, off, 64);
            }
            if (lq == 0) {
                int n = m * 16 + lg * 4 + r;
                lnred[n][w][0] = pv;
                lnred[n][w][1] = qv;
            }
        }
    }
    __syncthreads();

    // ---- finalize LN + ReLU + store ----
    float g0 = gamma[col0], g1 = gamma[col1];
    float be0 = beta[col0], be1 = beta[col1];
    #pragma unroll
    for (int m = 0; m < 4; ++m) {
        #pragma unroll
        for (int r = 0; r < 4; ++r) {
            int n = m * 16 + lg * 4 + r;
            float p = lnred[n][0][0] + lnred[n][1][0] + lnred[n][2][0] + lnred[n][3][0];
            float q = lnred[n][0][1] + lnred[n][1][1] + lnred[n][2][1] + lnred[n][3][1];
            float mu  = p * (1.0f / HID);
            float var = q * (1.0f / HID) - mu * mu;
            float rs = rsqrtf(var + 1e-5f);
            int node = node0 + n;
            if (node < N_NODES) {
                float o0 = fmaxf((acc[m][0][r] - mu) * rs * g0 + be0, 0.f);
                float o1 = fmaxf((acc[m][1][r] - mu) * rs * g1 + be1, 0.f);
                h_out[(size_t)node * HID + col0] = o0;
                h_out[(size_t)node * HID + col1] = o1;
            }
        }
    }
}

// ---------------- per-graph mean/max pool (graph_batch is sorted) ----------------
__global__ __launch_bounds__(128) void pool_kernel(
    const float* __restrict__ h, const int* __restrict__ gb,
    float* __restrict__ gsum, float* __restrict__ gmax, float* __restrict__ gcnt)
{
    int tid = threadIdx.x;
    int start = blockIdx.x * CHUNK;
    if (start >= N_NODES) return;
    int end = min(start + CHUNK, N_NODES);

    int curg = gb[start];
    float s = 0.f, m = 0.f;
    int c = 0;
    for (int node = start; node < end; ++node) {
        int g = gb[node];
        if (g != curg) {
            atomicAdd(&gsum[curg * HID + tid], s);
            atomicMax((int*)&gmax[curg * HID + tid], __float_as_int(m));
            if (tid == 0) atomicAdd(&gcnt[curg], (float)c);
            curg = g; s = 0.f; m = 0.f; c = 0;
        }
        float v = h[(size_t)node * HID + tid];
        s += v;
        m = fmaxf(m, v);
        ++c;
    }
    atomicAdd(&gsum[curg * HID + tid], s);
    atomicMax((int*)&gmax[curg * HID + tid], __float_as_int(m));
    if (tid == 0) atomicAdd(&gcnt[curg], (float)c);
}

// ---------------- readout MLP + L2 normalize ----------------
__global__ __launch_bounds__(256) void readout_kernel(
    const float* __restrict__ gsum, const float* __restrict__ gmax,
    const float* __restrict__ gcnt,
    const float* __restrict__ Wr1, const float* __restrict__ br1,
    const float* __restrict__ Wr2, const float* __restrict__ br2,
    float* __restrict__ out)
{
    __shared__ float pooled[2 * HID];
    __shared__ float hid[HID];
    __shared__ float red[4];

    int g = blockIdx.x, tid = threadIdx.x;

    if (tid < HID) {
        float n = fmaxf(gcnt[g], 1.0f);
        pooled[tid] = gsum[g * HID + tid] / n;
    } else {
        pooled[tid] = gmax[g * HID + (tid - HID)];
    }
    __syncthreads();

    if (tid < HID) {
        float a = br1[tid];
        for (int k = 0; k < 2 * HID; ++k)
            a += pooled[k] * Wr1[k * HID + tid];
        hid[tid] = fmaxf(a, 0.0f);
    }
    __syncthreads();

    float a = br2[tid];
    for (int k = 0; k < HID; ++k)
        a += hid[k] * Wr2[k * OUT_DIM + tid];

    float ss = a * a;
    #pragma unroll
    for (int off = 32; off >= 1; off >>= 1) ss += __shfl_xor(ss, off, 64);
    int wv = tid >> 6, lane = tid & 63;
    if (lane == 0) red[wv] = ss;
    __syncthreads();
    float tot = red[0] + red[1] + red[2] + red[3];
    float nrm = fmaxf(sqrtf(tot), 1e-12f);
    out[g * OUT_DIM + tid] = a / nrm;
}

extern "C" void kernel_launch(void* const* d_in, const int* in_sizes, int n_in,
                              void* d_out, int out_size, void* d_ws, size_t ws_size,
                              hipStream_t stream) {
    const float* x   = (const float*)d_in[0];
    const int*   ei  = (const int*)d_in[1];
    const int*   gb  = (const int*)d_in[2];
    const float* W1l = (const float*)d_in[3];
    const float* W1r = (const float*)d_in[4];
    const float* b1  = (const float*)d_in[5];
    const float* g1  = (const float*)d_in[6];
    const float* be1 = (const float*)d_in[7];
    const float* W2l = (const float*)d_in[8];
    const float* W2r = (const float*)d_in[9];
    const float* b2  = (const float*)d_in[10];
    const float* g2  = (const float*)d_in[11];
    const float* be2 = (const float*)d_in[12];
    const float* W3l = (const float*)d_in[13];
    const float* W3r = (const float*)d_in[14];
    const float* b3  = (const float*)d_in[15];
    const float* g3  = (const float*)d_in[16];
    const float* be3 = (const float*)d_in[17];
    const float* Wr1 = (const float*)d_in[18];
    const float* br1 = (const float*)d_in[19];
    const float* Wr2 = (const float*)d_in[20];
    const float* br2 = (const float*)d_in[21];

    const int* src = ei;
    const int* dst = ei + N_EDGES;

    char* ws = (char*)d_ws;
    size_t off = 0;
    auto alloc = [&](size_t bytes) -> void* {
        void* p = ws + off;
        off += (bytes + 255) & ~(size_t)255;
        return p;
    };
    float* hA      = (float*)alloc((size_t)N_NODES * HID * 4);
    float* hB      = (float*)alloc((size_t)N_NODES * HID * 4);
    int*   deg     = (int*)alloc((size_t)N_NODES * 4);
    int*   part    = (int*)alloc((size_t)SCAN_NB * SCAN_B * 4);
    int*   bsum    = (int*)alloc((size_t)SCAN_NB * 4);
    int*   boff    = (int*)alloc((size_t)SCAN_NB * 4);
    int*   row_ptr = (int*)alloc((size_t)(N_NODES + 1) * 4);
    int*   cursor  = (int*)alloc((size_t)N_NODES * 4);
    float* invdeg  = (float*)alloc((size_t)N_NODES * 4);
    int*   csr_src = (int*)alloc((size_t)N_EDGES * 4);
    float* gsum    = (float*)alloc((size_t)N_GRAPHS * HID * 4);
    float* gmax    = (float*)alloc((size_t)N_GRAPHS * HID * 4);
    float* gcnt    = (float*)alloc((size_t)N_GRAPHS * 4);
    unsigned short* wf1 = (unsigned short*)alloc(65536 * 2);
    unsigned short* wf2 = (unsigned short*)alloc(65536 * 2);
    unsigned short* wf3 = (unsigned short*)alloc(65536 * 2);

    // ---- build CSR (once) + weight prep ----
    hipMemsetAsync(deg, 0, (size_t)N_NODES * 4, stream);
    count_kernel<<<(N_EDGES + 255) / 256, 256, 0, stream>>>(dst, deg);
    scan1_kernel<<<SCAN_NB, SCAN_B, 0, stream>>>(deg, part, bsum);
    scan2_kernel<<<1, 256, 0, stream>>>(bsum, boff);
    scan3_kernel<<<SCAN_NB, SCAN_B, 0, stream>>>(part, boff, deg, row_ptr, cursor, invdeg);
    fill_kernel<<<(N_EDGES + 255) / 256, 256, 0, stream>>>(src, dst, cursor, csr_src);

    prep_w<<<128, 256, 0, stream>>>(W1l, W1r, wf1);
    prep_w<<<128, 256, 0, stream>>>(W2l, W2r, wf2);
    prep_w<<<128, 256, 0, stream>>>(W3l, W3r, wf3);

    const int sage_blocks = (N_NODES + BN - 1) / BN;   // 1563

    // ---- 3 fused SAGE layers ----
    sage_mfma<<<sage_blocks, 256, 0, stream>>>(x,  row_ptr, csr_src, invdeg, wf1, b1, g1, be1, hA);
    sage_mfma<<<sage_blocks, 256, 0, stream>>>(hA, row_ptr, csr_src, invdeg, wf2, b2, g2, be2, hB);
    sage_mfma<<<sage_blocks, 256, 0, stream>>>(hB, row_ptr, csr_src, invdeg, wf3, b3, g3, be3, hA);

    // ---- pooling ----
    hipMemsetAsync(gsum, 0, (size_t)N_GRAPHS * HID * 4, stream);
    hipMemsetAsync(gmax, 0, (size_t)N_GRAPHS * HID * 4, stream);
    hipMemsetAsync(gcnt, 0, (size_t)N_GRAPHS * 4, stream);
    pool_kernel<<<(N_NODES + CHUNK - 1) / CHUNK, 128, 0, stream>>>(hA, gb, gsum, gmax, gcnt);

    // ---- readout ----
    readout_kernel<<<N_GRAPHS, 256, 0, stream>>>(gsum, gmax, gcnt, Wr1, br1, Wr2, br2, (float*)d_out);
}

// Round 4
// 429.448 us; speedup vs baseline: 3.5690x; 1.5374x over previous
//
#include <hip/hip_runtime.h>
#include <hip/hip_bf16.h>

#define N_NODES 100000
#define N_EDGES 600000
#define HID 128
#define OUT_DIM 256
#define N_GRAPHS 256
#define BN 32            // nodes per block in fused SAGE kernel
#define LDA 260          // smA row stride in floats (odd in 16B units)
#define CHUNK 16
#define SCAN_B 512
#define SCAN_NB ((N_NODES + SCAN_B) / SCAN_B)

typedef __attribute__((ext_vector_type(8))) __bf16 bf16x8;
typedef __attribute__((ext_vector_type(4))) float f32x4;

__device__ inline f32x4 mfma16(bf16x8 a, bf16x8 b, f32x4 c) {
    return __builtin_amdgcn_mfma_f32_16x16x32_bf16(a, b, c, 0, 0, 0);
}

__device__ inline unsigned short bf_bits(__bf16 b) {
    union { __bf16 b; unsigned short u; } x; x.b = b; return x.u;
}

// ---------------- degree count ----------------
__global__ void count_kernel(const int* __restrict__ dst, int* __restrict__ deg) {
    int e = blockIdx.x * blockDim.x + threadIdx.x;
    if (e < N_EDGES) atomicAdd(&deg[dst[e]], 1);
}

// ---------------- block-level exclusive scan ----------------
__global__ __launch_bounds__(SCAN_B) void scan1_kernel(
    const int* __restrict__ deg, int* __restrict__ part, int* __restrict__ bsum)
{
    __shared__ int s[SCAN_B];
    int t = threadIdx.x;
    int i = blockIdx.x * SCAN_B + t;
    int v = (i < N_NODES) ? deg[i] : 0;
    s[t] = v;
    __syncthreads();
    #pragma unroll
    for (int off = 1; off < SCAN_B; off <<= 1) {
        int x = (t >= off) ? s[t - off] : 0;
        __syncthreads();
        s[t] += x;
        __syncthreads();
    }
    part[i] = s[t] - v;
    if (t == SCAN_B - 1) bsum[blockIdx.x] = s[t];
}

__global__ __launch_bounds__(256) void scan2_kernel(
    const int* __restrict__ bsum, int* __restrict__ boff)
{
    __shared__ int s[256];
    int t = threadIdx.x;
    int v = (t < SCAN_NB) ? bsum[t] : 0;
    s[t] = v;
    __syncthreads();
    #pragma unroll
    for (int off = 1; off < 256; off <<= 1) {
        int x = (t >= off) ? s[t - off] : 0;
        __syncthreads();
        s[t] += x;
        __syncthreads();
    }
    if (t < SCAN_NB) boff[t] = s[t] - v;
}

__global__ __launch_bounds__(SCAN_B) void scan3_kernel(
    const int* __restrict__ part, const int* __restrict__ boff,
    const int* __restrict__ deg,
    int* __restrict__ row_ptr, int* __restrict__ cursor, float* __restrict__ invdeg)
{
    int i = blockIdx.x * SCAN_B + threadIdx.x;
    int rp = part[i] + boff[blockIdx.x];
    if (i <= N_NODES) row_ptr[i] = rp;
    if (i < N_NODES) {
        cursor[i] = rp;
        invdeg[i] = 1.0f / (float)max(deg[i], 1);
    }
}

__global__ void fill_kernel(const int* __restrict__ src, const int* __restrict__ dst,
                            int* __restrict__ cursor, int* __restrict__ csr_src)
{
    int e = blockIdx.x * blockDim.x + threadIdx.x;
    if (e < N_EDGES) {
        int t = dst[e];
        int pos = atomicAdd(&cursor[t], 1);
        csr_src[pos] = src[e];
    }
}

// ---------------- weight prep: stacked [Wl;Wr] -> fragment-major bf16 hi/lo ----------------
// layout (ushort): p*32768 + ks*4096 + nf*512 + lane*8 + j
//   value = W[k = ks*32 + (lane>>4)*8 + j][c = nf*16 + (lane&15)], p0=hi, p1=lo
__global__ __launch_bounds__(256) void prep_w(const float* __restrict__ Wl,
                                              const float* __restrict__ Wr,
                                              unsigned short* __restrict__ wf)
{
    int flat = blockIdx.x * 256 + threadIdx.x;   // 32768 total
    int j  = flat & 7;
    int l  = (flat >> 3) & 63;
    int nf = (flat >> 9) & 7;
    int ks = flat >> 12;
    int k = ks * 32 + ((l >> 4) << 3) + j;
    int c = nf * 16 + (l & 15);
    float v = (k < HID) ? Wl[k * HID + c] : Wr[(k - HID) * HID + c];
    __bf16 hi = (__bf16)v;
    __bf16 lo = (__bf16)(v - (float)hi);
    wf[flat]         = bf_bits(hi);
    wf[32768 + flat] = bf_bits(lo);
}

// ---------------- fused gather + split-bf16 MFMA GEMM + LayerNorm + ReLU ----------------
__global__ __launch_bounds__(256, 4) void sage_mfma(
    const float* __restrict__ h_in,
    const int* __restrict__ row_ptr, const int* __restrict__ csr_src,
    const float* __restrict__ invdeg,
    const unsigned short* __restrict__ wf,
    const float* __restrict__ bias, const float* __restrict__ gamma,
    const float* __restrict__ beta,
    float* __restrict__ h_out)
{
    __shared__ float smA[BN * LDA];          // 33.3 KB: [node][k], k0-127 agg, k128-255 root
    __shared__ float lnred[BN][4][2];        // 1 KB cross-wave LN partials

    const int tid  = threadIdx.x;
    const int lane = tid & 63;
    const int w    = tid >> 6;
    const int lq   = lane & 15;
    const int lg   = lane >> 4;
    const int node0 = blockIdx.x * BN;

    // ---- stage root h into smA[n][128..255] (coalesced float4) ----
    for (int i = tid; i < BN * 32; i += 256) {
        int n = i >> 5, c = (i & 31) * 4;
        float4 v = *(const float4*)(h_in + (size_t)(node0 + n) * HID + c);
        *(float4*)&smA[n * LDA + HID + c] = v;
    }

    // ---- gather neighbor mean into smA[n][0..127] ----
    // half-wave per edge (32 lanes x float4 = full 512B row), 4-deep unroll
    {
        const int half = lane >> 5;
        const int hl   = lane & 31;
        const int d0   = hl * 4;
        for (int n = w * 8; n < w * 8 + 8; ++n) {
            int node = node0 + n;
            f32x4 a0 = {0.f, 0.f, 0.f, 0.f}, a1 = a0, a2 = a0, a3 = a0;
            int e = row_ptr[node], r1 = row_ptr[node + 1];
            // 8 edges in flight (2 per step x 4 slots)
            for (; e + 8 <= r1; e += 8) {
                int s0 = csr_src[e     + half];
                int s1 = csr_src[e + 2 + half];
                int s2 = csr_src[e + 4 + half];
                int s3 = csr_src[e + 6 + half];
                a0 += *(const f32x4*)(h_in + (size_t)s0 * HID + d0);
                a1 += *(const f32x4*)(h_in + (size_t)s1 * HID + d0);
                a2 += *(const f32x4*)(h_in + (size_t)s2 * HID + d0);
                a3 += *(const f32x4*)(h_in + (size_t)s3 * HID + d0);
            }
            for (; e + 4 <= r1; e += 4) {
                int s0 = csr_src[e     + half];
                int s1 = csr_src[e + 2 + half];
                a0 += *(const f32x4*)(h_in + (size_t)s0 * HID + d0);
                a1 += *(const f32x4*)(h_in + (size_t)s1 * HID + d0);
            }
            for (; e < r1; e += 2) {
                if (e + half < r1) {
                    int s0 = csr_src[e + half];
                    a0 += *(const f32x4*)(h_in + (size_t)s0 * HID + d0);
                }
            }
            f32x4 a = (a0 + a1) + (a2 + a3);
            a.x += __shfl_xor(a.x, 32, 64);
            a.y += __shfl_xor(a.y, 32, 64);
            a.z += __shfl_xor(a.z, 32, 64);
            a.w += __shfl_xor(a.w, 32, 64);
            float inv = invdeg[node];
            a *= inv;
            if (half == 0) *(f32x4*)&smA[n * LDA + d0] = a;
        }
    }
    __syncthreads();

    // ---- split-bf16 MFMA GEMM: out[32 x 128] = A[32 x 256] @ W[256 x 128] ----
    const int nf0 = w * 2;
    const int col0 = nf0 * 16 + lq;          // = w*32 + lq
    const int col1 = col0 + 16;

    f32x4 acc[2][2];
    {
        float b0 = bias[col0], b1 = bias[col1];
        #pragma unroll
        for (int m = 0; m < 2; ++m) {
            acc[m][0] = (f32x4){b0, b0, b0, b0};
            acc[m][1] = (f32x4){b1, b1, b1, b1};
        }
    }

    const bf16x8* wfv = (const bf16x8*)wf;
    #pragma unroll 2
    for (int ks = 0; ks < 8; ++ks) {
        int base = (ks << 9) + nf0 * 64 + lane;      // ushort8 units
        bf16x8 bh0 = wfv[base];
        bf16x8 bh1 = wfv[base + 64];
        bf16x8 bl0 = wfv[base + 4096];
        bf16x8 bl1 = wfv[base + 4096 + 64];
        #pragma unroll
        for (int m = 0; m < 2; ++m) {
            const float* ap = &smA[(m * 16 + lq) * LDA + (ks << 5) + (lg << 3)];
            float4 a0 = *(const float4*)ap;
            float4 a1 = *(const float4*)(ap + 4);
            float av[8] = {a0.x, a0.y, a0.z, a0.w, a1.x, a1.y, a1.z, a1.w};
            bf16x8 ahi, alo;
            #pragma unroll
            for (int j = 0; j < 8; ++j) {
                __bf16 h = (__bf16)av[j];
                ahi[j] = h;
                alo[j] = (__bf16)(av[j] - (float)h);
            }
            acc[m][0] = mfma16(ahi, bh0, acc[m][0]);
            acc[m][0] = mfma16(alo, bh0, acc[m][0]);
            acc[m][0] = mfma16(ahi, bl0, acc[m][0]);
            acc[m][1] = mfma16(ahi, bh1, acc[m][1]);
            acc[m][1] = mfma16(alo, bh1, acc[m][1]);
            acc[m][1] = mfma16(ahi, bl1, acc[m][1]);
        }
    }

    // ---- LayerNorm partials: value (m, r) sits at node m*16+lg*4+r ----
    #pragma unroll
    for (int m = 0; m < 2; ++m) {
        #pragma unroll
        for (int r = 0; r < 4; ++r) {
            float pv = acc[m][0][r] + acc[m][1][r];
            float qv = acc[m][0][r] * acc[m][0][r] + acc[m][1][r] * acc[m][1][r];
            #pragma unroll
            for (int off = 8; off >= 1; off >>= 1) {
                pv += __shfl_xor(pv, off, 64);
                qv += __shfl_xor(qv, off, 64);
            }
            if (lq == 0) {
                int n = m * 16 + lg * 4 + r;
                lnred[n][w][0] = pv;
                lnred[n][w][1] = qv;
            }
        }
    }
    __syncthreads();

    // ---- finalize LN + ReLU + store ----
    float g0 = gamma[col0], g1 = gamma[col1];
    float be0 = beta[col0], be1 = beta[col1];
    #pragma unroll
    for (int m = 0; m < 2; ++m) {
        #pragma unroll
        for (int r = 0; r < 4; ++r) {
            int n = m * 16 + lg * 4 + r;
            float p = lnred[n][0][0] + lnred[n][1][0] + lnred[n][2][0] + lnred[n][3][0];
            float q = lnred[n][0][1] + lnred[n][1][1] + lnred[n][2][1] + lnred[n][3][1];
            float mu  = p * (1.0f / HID);
            float var = q * (1.0f / HID) - mu * mu;
            float rs = rsqrtf(var + 1e-5f);
            int node = node0 + n;
            float o0 = fmaxf((acc[m][0][r] - mu) * rs * g0 + be0, 0.f);
            float o1 = fmaxf((acc[m][1][r] - mu) * rs * g1 + be1, 0.f);
            h_out[(size_t)node * HID + col0] = o0;
            h_out[(size_t)node * HID + col1] = o1;
        }
    }
}

// ---------------- per-graph mean/max pool (graph_batch is sorted) ----------------
__global__ __launch_bounds__(128) void pool_kernel(
    const float* __restrict__ h, const int* __restrict__ gb,
    float* __restrict__ gsum, float* __restrict__ gmax, float* __restrict__ gcnt)
{
    int tid = threadIdx.x;
    int start = blockIdx.x * CHUNK;
    if (start >= N_NODES) return;
    int end = min(start + CHUNK, N_NODES);

    int curg = gb[start];
    float s = 0.f, m = 0.f;
    int c = 0;
    for (int node = start; node < end; ++node) {
        int g = gb[node];
        if (g != curg) {
            atomicAdd(&gsum[curg * HID + tid], s);
            atomicMax((int*)&gmax[curg * HID + tid], __float_as_int(m));
            if (tid == 0) atomicAdd(&gcnt[curg], (float)c);
            curg = g; s = 0.f; m = 0.f; c = 0;
        }
        float v = h[(size_t)node * HID + tid];
        s += v;
        m = fmaxf(m, v);
        ++c;
    }
    atomicAdd(&gsum[curg * HID + tid], s);
    atomicMax((int*)&gmax[curg * HID + tid], __float_as_int(m));
    if (tid == 0) atomicAdd(&gcnt[curg], (float)c);
}

// ---------------- readout MLP + L2 normalize ----------------
__global__ __launch_bounds__(256) void readout_kernel(
    const float* __restrict__ gsum, const float* __restrict__ gmax,
    const float* __restrict__ gcnt,
    const float* __restrict__ Wr1, const float* __restrict__ br1,
    const float* __restrict__ Wr2, const float* __restrict__ br2,
    float* __restrict__ out)
{
    __shared__ float pooled[2 * HID];
    __shared__ float hid[HID];
    __shared__ float red[4];

    int g = blockIdx.x, tid = threadIdx.x;

    if (tid < HID) {
        float n = fmaxf(gcnt[g], 1.0f);
        pooled[tid] = gsum[g * HID + tid] / n;
    } else {
        pooled[tid] = gmax[g * HID + (tid - HID)];
    }
    __syncthreads();

    if (tid < HID) {
        float a = br1[tid];
        for (int k = 0; k < 2 * HID; ++k)
            a += pooled[k] * Wr1[k * HID + tid];
        hid[tid] = fmaxf(a, 0.0f);
    }
    __syncthreads();

    float a = br2[tid];
    for (int k = 0; k < HID; ++k)
        a += hid[k] * Wr2[k * OUT_DIM + tid];

    float ss = a * a;
    #pragma unroll
    for (int off = 32; off >= 1; off >>= 1) ss += __shfl_xor(ss, off, 64);
    int wv = tid >> 6, lane = tid & 63;
    if (lane == 0) red[wv] = ss;
    __syncthreads();
    float tot = red[0] + red[1] + red[2] + red[3];
    float nrm = fmaxf(sqrtf(tot), 1e-12f);
    out[g * OUT_DIM + tid] = a / nrm;
}

extern "C" void kernel_launch(void* const* d_in, const int* in_sizes, int n_in,
                              void* d_out, int out_size, void* d_ws, size_t ws_size,
                              hipStream_t stream) {
    const float* x   = (const float*)d_in[0];
    const int*   ei  = (const int*)d_in[1];
    const int*   gb  = (const int*)d_in[2];
    const float* W1l = (const float*)d_in[3];
    const float* W1r = (const float*)d_in[4];
    const float* b1  = (const float*)d_in[5];
    const float* g1  = (const float*)d_in[6];
    const float* be1 = (const float*)d_in[7];
    const float* W2l = (const float*)d_in[8];
    const float* W2r = (const float*)d_in[9];
    const float* b2  = (const float*)d_in[10];
    const float* g2  = (const float*)d_in[11];
    const float* be2 = (const float*)d_in[12];
    const float* W3l = (const float*)d_in[13];
    const float* W3r = (const float*)d_in[14];
    const float* b3  = (const float*)d_in[15];
    const float* g3  = (const float*)d_in[16];
    const float* be3 = (const float*)d_in[17];
    const float* Wr1 = (const float*)d_in[18];
    const float* br1 = (const float*)d_in[19];
    const float* Wr2 = (const float*)d_in[20];
    const float* br2 = (const float*)d_in[21];

    const int* src = ei;
    const int* dst = ei + N_EDGES;

    char* ws = (char*)d_ws;
    size_t off = 0;
    auto alloc = [&](size_t bytes) -> void* {
        void* p = ws + off;
        off += (bytes + 255) & ~(size_t)255;
        return p;
    };
    float* hA      = (float*)alloc((size_t)N_NODES * HID * 4);
    float* hB      = (float*)alloc((size_t)N_NODES * HID * 4);
    int*   deg     = (int*)alloc((size_t)N_NODES * 4);
    int*   part    = (int*)alloc((size_t)SCAN_NB * SCAN_B * 4);
    int*   bsum    = (int*)alloc((size_t)SCAN_NB * 4);
    int*   boff    = (int*)alloc((size_t)SCAN_NB * 4);
    int*   row_ptr = (int*)alloc((size_t)(N_NODES + 1) * 4);
    int*   cursor  = (int*)alloc((size_t)N_NODES * 4);
    float* invdeg  = (float*)alloc((size_t)N_NODES * 4);
    int*   csr_src = (int*)alloc((size_t)N_EDGES * 4);
    float* gsum    = (float*)alloc((size_t)N_GRAPHS * HID * 4);
    float* gmax    = (float*)alloc((size_t)N_GRAPHS * HID * 4);
    float* gcnt    = (float*)alloc((size_t)N_GRAPHS * 4);
    unsigned short* wf1 = (unsigned short*)alloc(65536 * 2);
    unsigned short* wf2 = (unsigned short*)alloc(65536 * 2);
    unsigned short* wf3 = (unsigned short*)alloc(65536 * 2);

    // ---- build CSR (once) + weight prep ----
    hipMemsetAsync(deg, 0, (size_t)N_NODES * 4, stream);
    count_kernel<<<(N_EDGES + 255) / 256, 256, 0, stream>>>(dst, deg);
    scan1_kernel<<<SCAN_NB, SCAN_B, 0, stream>>>(deg, part, bsum);
    scan2_kernel<<<1, 256, 0, stream>>>(bsum, boff);
    scan3_kernel<<<SCAN_NB, SCAN_B, 0, stream>>>(part, boff, deg, row_ptr, cursor, invdeg);
    fill_kernel<<<(N_EDGES + 255) / 256, 256, 0, stream>>>(src, dst, cursor, csr_src);

    prep_w<<<128, 256, 0, stream>>>(W1l, W1r, wf1);
    prep_w<<<128, 256, 0, stream>>>(W2l, W2r, wf2);
    prep_w<<<128, 256, 0, stream>>>(W3l, W3r, wf3);

    const int sage_blocks = N_NODES / BN;   // 3125, exact

    // ---- 3 fused SAGE layers ----
    sage_mfma<<<sage_blocks, 256, 0, stream>>>(x,  row_ptr, csr_src, invdeg, wf1, b1, g1, be1, hA);
    sage_mfma<<<sage_blocks, 256, 0, stream>>>(hA, row_ptr, csr_src, invdeg, wf2, b2, g2, be2, hB);
    sage_mfma<<<sage_blocks, 256, 0, stream>>>(hB, row_ptr, csr_src, invdeg, wf3, b3, g3, be3, hA);

    // ---- pooling ----
    hipMemsetAsync(gsum, 0, (size_t)N_GRAPHS * HID * 4, stream);
    hipMemsetAsync(gmax, 0, (size_t)N_GRAPHS * HID * 4, stream);
    hipMemsetAsync(gcnt, 0, (size_t)N_GRAPHS * 4, stream);
    pool_kernel<<<(N_NODES + CHUNK - 1) / CHUNK, 128, 0, stream>>>(hA, gb, gsum, gmax, gcnt);

    // ---- readout ----
    readout_kernel<<<N_GRAPHS, 256, 0, stream>>>(gsum, gmax, gcnt, Wr1, br1, Wr2, br2, (float*)d_out);
}

// Round 5
// 402.594 us; speedup vs baseline: 3.8070x; 1.0667x over previous
//
#include <hip/hip_runtime.h>
#include <hip/hip_bf16.h>

#define N_NODES 100000
#define N_EDGES 600000
#define HID 128
#define OUT_DIM 256
#define N_GRAPHS 256
#define BN 32            // nodes per block in fused SAGE kernel
#define LDA2 132         // smA row stride in floats (132%32=4; matches prior conflict level)
#define CHUNK 16
#define SCAN_B 512
#define SCAN_NB ((N_NODES + SCAN_B) / SCAN_B)

typedef __attribute__((ext_vector_type(8))) __bf16 bf16x8;
typedef __attribute__((ext_vector_type(4))) float f32x4;

__device__ inline f32x4 mfma16(bf16x8 a, bf16x8 b, f32x4 c) {
    return __builtin_amdgcn_mfma_f32_16x16x32_bf16(a, b, c, 0, 0, 0);
}

__device__ inline unsigned short bf_bits(__bf16 b) {
    union { __bf16 b; unsigned short u; } x; x.b = b; return x.u;
}

// ---------------- degree count ----------------
__global__ void count_kernel(const int* __restrict__ dst, int* __restrict__ deg) {
    int e = blockIdx.x * blockDim.x + threadIdx.x;
    if (e < N_EDGES) atomicAdd(&deg[dst[e]], 1);
}

// ---------------- block-level exclusive scan ----------------
__global__ __launch_bounds__(SCAN_B) void scan1_kernel(
    const int* __restrict__ deg, int* __restrict__ part, int* __restrict__ bsum)
{
    __shared__ int s[SCAN_B];
    int t = threadIdx.x;
    int i = blockIdx.x * SCAN_B + t;
    int v = (i < N_NODES) ? deg[i] : 0;
    s[t] = v;
    __syncthreads();
    #pragma unroll
    for (int off = 1; off < SCAN_B; off <<= 1) {
        int x = (t >= off) ? s[t - off] : 0;
        __syncthreads();
        s[t] += x;
        __syncthreads();
    }
    part[i] = s[t] - v;
    if (t == SCAN_B - 1) bsum[blockIdx.x] = s[t];
}

__global__ __launch_bounds__(256) void scan2_kernel(
    const int* __restrict__ bsum, int* __restrict__ boff)
{
    __shared__ int s[256];
    int t = threadIdx.x;
    int v = (t < SCAN_NB) ? bsum[t] : 0;
    s[t] = v;
    __syncthreads();
    #pragma unroll
    for (int off = 1; off < 256; off <<= 1) {
        int x = (t >= off) ? s[t - off] : 0;
        __syncthreads();
        s[t] += x;
        __syncthreads();
    }
    if (t < SCAN_NB) boff[t] = s[t] - v;
}

__global__ __launch_bounds__(SCAN_B) void scan3_kernel(
    const int* __restrict__ part, const int* __restrict__ boff,
    const int* __restrict__ deg,
    int* __restrict__ row_ptr, int* __restrict__ cursor, float* __restrict__ invdeg)
{
    int i = blockIdx.x * SCAN_B + threadIdx.x;
    int rp = part[i] + boff[blockIdx.x];
    if (i <= N_NODES) row_ptr[i] = rp;
    if (i < N_NODES) {
        cursor[i] = rp;
        invdeg[i] = 1.0f / (float)max(deg[i], 1);
    }
}

__global__ void fill_kernel(const int* __restrict__ src, const int* __restrict__ dst,
                            int* __restrict__ cursor, int* __restrict__ csr_src)
{
    int e = blockIdx.x * blockDim.x + threadIdx.x;
    if (e < N_EDGES) {
        int t = dst[e];
        int pos = atomicAdd(&cursor[t], 1);
        csr_src[pos] = src[e];
    }
}

// ---------------- weight prep: stacked [Wl;Wr] -> fragment-major bf16 hi/lo ----------------
// layout (ushort): p*32768 + ks*4096 + nf*512 + lane*8 + j
//   value = W[k = ks*32 + (lane>>4)*8 + j][c = nf*16 + (lane&15)], p0=hi, p1=lo
__global__ __launch_bounds__(256) void prep_w(const float* __restrict__ Wl,
                                              const float* __restrict__ Wr,
                                              unsigned short* __restrict__ wf)
{
    int flat = blockIdx.x * 256 + threadIdx.x;   // 32768 total
    int j  = flat & 7;
    int l  = (flat >> 3) & 63;
    int nf = (flat >> 9) & 7;
    int ks = flat >> 12;
    int k = ks * 32 + ((l >> 4) << 3) + j;
    int c = nf * 16 + (l & 15);
    float v = (k < HID) ? Wl[k * HID + c] : Wr[(k - HID) * HID + c];
    __bf16 hi = (__bf16)v;
    __bf16 lo = (__bf16)(v - (float)hi);
    wf[flat]         = bf_bits(hi);
    wf[32768 + flat] = bf_bits(lo);
}

// ---------------- fused gather + split-bf16 MFMA GEMM + LayerNorm + ReLU ----------------
__global__ __launch_bounds__(256, 8) void sage_mfma(
    const float* __restrict__ h_in,
    const int* __restrict__ row_ptr, const int* __restrict__ csr_src,
    const float* __restrict__ invdeg,
    const unsigned short* __restrict__ wf,
    const float* __restrict__ bias, const float* __restrict__ gamma,
    const float* __restrict__ beta,
    float* __restrict__ h_out)
{
    __shared__ float smA[BN * LDA2];         // 16.9 KB: [node][k0..127] aggregated means
    __shared__ float lnred[BN][4][2];        // 1 KB cross-wave LN partials

    const int tid  = threadIdx.x;
    const int lane = tid & 63;
    const int w    = tid >> 6;
    const int lq   = lane & 15;
    const int lg   = lane >> 4;
    const int node0 = blockIdx.x * BN;

    // ---- gather neighbor mean into smA[n][0..127] ----
    // One vector load grabs all (<=32) neighbor indices of a node; per-edge index
    // comes from __shfl (register, no memory latency) -> data loads pipeline freely.
    {
        const int half = lane >> 5;          // which half-wave
        const int hl   = lane & 31;
        const int d0   = hl * 4;             // this lane's 4-dim slice (half-wave = full row)
        for (int n = w * 8; n < w * 8 + 8; ++n) {
            int node = node0 + n;
            int r0  = row_ptr[node];
            int deg = row_ptr[node + 1] - r0;
            int idx = csr_src[min(r0 + hl, N_EDGES - 1)];   // lane hl holds index of edge-slot hl
            int dc  = min(deg, 32);
            f32x4 a0 = {0.f, 0.f, 0.f, 0.f}, a1 = a0, a2 = a0, a3 = a0;
            int s = half;
            for (; s + 6 < dc; s += 8) {     // slots s, s+2, s+4, s+6 per half = 8 edges/iter
                int i0 = __shfl(idx, s,     32);
                int i1 = __shfl(idx, s + 2, 32);
                int i2 = __shfl(idx, s + 4, 32);
                int i3 = __shfl(idx, s + 6, 32);
                a0 += *(const f32x4*)(h_in + (size_t)i0 * HID + d0);
                a1 += *(const f32x4*)(h_in + (size_t)i1 * HID + d0);
                a2 += *(const f32x4*)(h_in + (size_t)i2 * HID + d0);
                a3 += *(const f32x4*)(h_in + (size_t)i3 * HID + d0);
            }
            for (; s < dc; s += 2) {
                int i0 = __shfl(idx, s, 32);
                a0 += *(const f32x4*)(h_in + (size_t)i0 * HID + d0);
            }
            for (int t2 = 32 + half; t2 < deg; t2 += 2) {   // ~never (P(deg>32) ~ 1e-12)
                int i0 = csr_src[r0 + t2];
                a0 += *(const f32x4*)(h_in + (size_t)i0 * HID + d0);
            }
            f32x4 a = (a0 + a1) + (a2 + a3);
            a.x += __shfl_xor(a.x, 32, 64);
            a.y += __shfl_xor(a.y, 32, 64);
            a.z += __shfl_xor(a.z, 32, 64);
            a.w += __shfl_xor(a.w, 32, 64);
            a *= invdeg[node];
            if (half == 0) *(f32x4*)&smA[n * LDA2 + d0] = a;
        }
    }
    __syncthreads();

    // ---- split-bf16 MFMA GEMM: out[32 x 128] = [agg|root][32 x 256] @ W[256 x 128] ----
    // agg half (ks 0..3) from LDS; root half (ks 4..7) straight from global (each byte
    // read exactly once per block -> staging it in LDS saved nothing).
    const int nf0 = w * 2;
    const int col0 = nf0 * 16 + lq;          // = w*32 + lq
    const int col1 = col0 + 16;

    f32x4 acc[2][2];
    {
        float b0 = bias[col0], b1 = bias[col1];
        #pragma unroll
        for (int m = 0; m < 2; ++m) {
            acc[m][0] = (f32x4){b0, b0, b0, b0};
            acc[m][1] = (f32x4){b1, b1, b1, b1};
        }
    }

    const bf16x8* wfv = (const bf16x8*)wf;
    #pragma unroll 2
    for (int ks = 0; ks < 8; ++ks) {
        int base = (ks << 9) + nf0 * 64 + lane;      // ushort8 units
        bf16x8 bh0 = wfv[base];
        bf16x8 bh1 = wfv[base + 64];
        bf16x8 bl0 = wfv[base + 4096];
        bf16x8 bl1 = wfv[base + 4096 + 64];
        #pragma unroll
        for (int m = 0; m < 2; ++m) {
            float4 a0, a1;
            if (ks < 4) {
                const float* ap = &smA[(m * 16 + lq) * LDA2 + (ks << 5) + (lg << 3)];
                a0 = *(const float4*)ap;
                a1 = *(const float4*)(ap + 4);
            } else {
                const float* rp = h_in + (size_t)(node0 + m * 16 + lq) * HID
                                + ((ks - 4) << 5) + (lg << 3);
                a0 = *(const float4*)rp;
                a1 = *(const float4*)(rp + 4);
            }
            float av[8] = {a0.x, a0.y, a0.z, a0.w, a1.x, a1.y, a1.z, a1.w};
            bf16x8 ahi, alo;
            #pragma unroll
            for (int j = 0; j < 8; ++j) {
                __bf16 h = (__bf16)av[j];
                ahi[j] = h;
                alo[j] = (__bf16)(av[j] - (float)h);
            }
            acc[m][0] = mfma16(ahi, bh0, acc[m][0]);
            acc[m][0] = mfma16(alo, bh0, acc[m][0]);
            acc[m][0] = mfma16(ahi, bl0, acc[m][0]);
            acc[m][1] = mfma16(ahi, bh1, acc[m][1]);
            acc[m][1] = mfma16(alo, bh1, acc[m][1]);
            acc[m][1] = mfma16(ahi, bl1, acc[m][1]);
        }
    }

    // ---- LayerNorm partials: value (m, r) sits at node m*16+lg*4+r ----
    #pragma unroll
    for (int m = 0; m < 2; ++m) {
        #pragma unroll
        for (int r = 0; r < 4; ++r) {
            float pv = acc[m][0][r] + acc[m][1][r];
            float qv = acc[m][0][r] * acc[m][0][r] + acc[m][1][r] * acc[m][1][r];
            #pragma unroll
            for (int off = 8; off >= 1; off >>= 1) {
                pv += __shfl_xor(pv, off, 64);
                qv += __shfl_xor(qv, off, 64);
            }
            if (lq == 0) {
                int n = m * 16 + lg * 4 + r;
                lnred[n][w][0] = pv;
                lnred[n][w][1] = qv;
            }
        }
    }
    __syncthreads();

    // ---- finalize LN + ReLU + store ----
    float g0 = gamma[col0], g1 = gamma[col1];
    float be0 = beta[col0], be1 = beta[col1];
    #pragma unroll
    for (int m = 0; m < 2; ++m) {
        #pragma unroll
        for (int r = 0; r < 4; ++r) {
            int n = m * 16 + lg * 4 + r;
            float p = lnred[n][0][0] + lnred[n][1][0] + lnred[n][2][0] + lnred[n][3][0];
            float q = lnred[n][0][1] + lnred[n][1][1] + lnred[n][2][1] + lnred[n][3][1];
            float mu  = p * (1.0f / HID);
            float var = q * (1.0f / HID) - mu * mu;
            float rs = rsqrtf(var + 1e-5f);
            int node = node0 + n;
            float o0 = fmaxf((acc[m][0][r] - mu) * rs * g0 + be0, 0.f);
            float o1 = fmaxf((acc[m][1][r] - mu) * rs * g1 + be1, 0.f);
            h_out[(size_t)node * HID + col0] = o0;
            h_out[(size_t)node * HID + col1] = o1;
        }
    }
}

// ---------------- per-graph mean/max pool (graph_batch is sorted) ----------------
__global__ __launch_bounds__(128) void pool_kernel(
    const float* __restrict__ h, const int* __restrict__ gb,
    float* __restrict__ gsum, float* __restrict__ gmax, float* __restrict__ gcnt)
{
    int tid = threadIdx.x;
    int start = blockIdx.x * CHUNK;
    if (start >= N_NODES) return;
    int end = min(start + CHUNK, N_NODES);

    int curg = gb[start];
    float s = 0.f, m = 0.f;
    int c = 0;
    for (int node = start; node < end; ++node) {
        int g = gb[node];
        if (g != curg) {
            atomicAdd(&gsum[curg * HID + tid], s);
            atomicMax((int*)&gmax[curg * HID + tid], __float_as_int(m));
            if (tid == 0) atomicAdd(&gcnt[curg], (float)c);
            curg = g; s = 0.f; m = 0.f; c = 0;
        }
        float v = h[(size_t)node * HID + tid];
        s += v;
        m = fmaxf(m, v);
        ++c;
    }
    atomicAdd(&gsum[curg * HID + tid], s);
    atomicMax((int*)&gmax[curg * HID + tid], __float_as_int(m));
    if (tid == 0) atomicAdd(&gcnt[curg], (float)c);
}

// ---------------- readout MLP + L2 normalize ----------------
__global__ __launch_bounds__(256) void readout_kernel(
    const float* __restrict__ gsum, const float* __restrict__ gmax,
    const float* __restrict__ gcnt,
    const float* __restrict__ Wr1, const float* __restrict__ br1,
    const float* __restrict__ Wr2, const float* __restrict__ br2,
    float* __restrict__ out)
{
    __shared__ float pooled[2 * HID];
    __shared__ float hid[HID];
    __shared__ float red[4];

    int g = blockIdx.x, tid = threadIdx.x;

    if (tid < HID) {
        float n = fmaxf(gcnt[g], 1.0f);
        pooled[tid] = gsum[g * HID + tid] / n;
    } else {
        pooled[tid] = gmax[g * HID + (tid - HID)];
    }
    __syncthreads();

    if (tid < HID) {
        float a = br1[tid];
        for (int k = 0; k < 2 * HID; ++k)
            a += pooled[k] * Wr1[k * HID + tid];
        hid[tid] = fmaxf(a, 0.0f);
    }
    __syncthreads();

    float a = br2[tid];
    for (int k = 0; k < HID; ++k)
        a += hid[k] * Wr2[k * OUT_DIM + tid];

    float ss = a * a;
    #pragma unroll
    for (int off = 32; off >= 1; off >>= 1) ss += __shfl_xor(ss, off, 64);
    int wv = tid >> 6, lane = tid & 63;
    if (lane == 0) red[wv] = ss;
    __syncthreads();
    float tot = red[0] + red[1] + red[2] + red[3];
    float nrm = fmaxf(sqrtf(tot), 1e-12f);
    out[g * OUT_DIM + tid] = a / nrm;
}

extern "C" void kernel_launch(void* const* d_in, const int* in_sizes, int n_in,
                              void* d_out, int out_size, void* d_ws, size_t ws_size,
                              hipStream_t stream) {
    const float* x   = (const float*)d_in[0];
    const int*   ei  = (const int*)d_in[1];
    const int*   gb  = (const int*)d_in[2];
    const float* W1l = (const float*)d_in[3];
    const float* W1r = (const float*)d_in[4];
    const float* b1  = (const float*)d_in[5];
    const float* g1  = (const float*)d_in[6];
    const float* be1 = (const float*)d_in[7];
    const float* W2l = (const float*)d_in[8];
    const float* W2r = (const float*)d_in[9];
    const float* b2  = (const float*)d_in[10];
    const float* g2  = (const float*)d_in[11];
    const float* be2 = (const float*)d_in[12];
    const float* W3l = (const float*)d_in[13];
    const float* W3r = (const float*)d_in[14];
    const float* b3  = (const float*)d_in[15];
    const float* g3  = (const float*)d_in[16];
    const float* be3 = (const float*)d_in[17];
    const float* Wr1 = (const float*)d_in[18];
    const float* br1 = (const float*)d_in[19];
    const float* Wr2 = (const float*)d_in[20];
    const float* br2 = (const float*)d_in[21];

    const int* src = ei;
    const int* dst = ei + N_EDGES;

    char* ws = (char*)d_ws;
    size_t off = 0;
    auto alloc = [&](size_t bytes) -> void* {
        void* p = ws + off;
        off += (bytes + 255) & ~(size_t)255;
        return p;
    };
    float* hA      = (float*)alloc((size_t)N_NODES * HID * 4);
    float* hB      = (float*)alloc((size_t)N_NODES * HID * 4);
    int*   deg     = (int*)alloc((size_t)N_NODES * 4);
    int*   part    = (int*)alloc((size_t)SCAN_NB * SCAN_B * 4);
    int*   bsum    = (int*)alloc((size_t)SCAN_NB * 4);
    int*   boff    = (int*)alloc((size_t)SCAN_NB * 4);
    int*   row_ptr = (int*)alloc((size_t)(N_NODES + 1) * 4);
    int*   cursor  = (int*)alloc((size_t)N_NODES * 4);
    float* invdeg  = (float*)alloc((size_t)N_NODES * 4);
    int*   csr_src = (int*)alloc((size_t)N_EDGES * 4);
    float* gsum    = (float*)alloc((size_t)N_GRAPHS * HID * 4);
    float* gmax    = (float*)alloc((size_t)N_GRAPHS * HID * 4);
    float* gcnt    = (float*)alloc((size_t)N_GRAPHS * 4);
    unsigned short* wf1 = (unsigned short*)alloc(65536 * 2);
    unsigned short* wf2 = (unsigned short*)alloc(65536 * 2);
    unsigned short* wf3 = (unsigned short*)alloc(65536 * 2);

    // ---- build CSR (once) + weight prep ----
    hipMemsetAsync(deg, 0, (size_t)N_NODES * 4, stream);
    count_kernel<<<(N_EDGES + 255) / 256, 256, 0, stream>>>(dst, deg);
    scan1_kernel<<<SCAN_NB, SCAN_B, 0, stream>>>(deg, part, bsum);
    scan2_kernel<<<1, 256, 0, stream>>>(bsum, boff);
    scan3_kernel<<<SCAN_NB, SCAN_B, 0, stream>>>(part, boff, deg, row_ptr, cursor, invdeg);
    fill_kernel<<<(N_EDGES + 255) / 256, 256, 0, stream>>>(src, dst, cursor, csr_src);

    prep_w<<<128, 256, 0, stream>>>(W1l, W1r, wf1);
    prep_w<<<128, 256, 0, stream>>>(W2l, W2r, wf2);
    prep_w<<<128, 256, 0, stream>>>(W3l, W3r, wf3);

    const int sage_blocks = N_NODES / BN;   // 3125, exact

    // ---- 3 fused SAGE layers ----
    sage_mfma<<<sage_blocks, 256, 0, stream>>>(x,  row_ptr, csr_src, invdeg, wf1, b1, g1, be1, hA);
    sage_mfma<<<sage_blocks, 256, 0, stream>>>(hA, row_ptr, csr_src, invdeg, wf2, b2, g2, be2, hB);
    sage_mfma<<<sage_blocks, 256, 0, stream>>>(hB, row_ptr, csr_src, invdeg, wf3, b3, g3, be3, hA);

    // ---- pooling ----
    hipMemsetAsync(gsum, 0, (size_t)N_GRAPHS * HID * 4, stream);
    hipMemsetAsync(gmax, 0, (size_t)N_GRAPHS * HID * 4, stream);
    hipMemsetAsync(gcnt, 0, (size_t)N_GRAPHS * 4, stream);
    pool_kernel<<<(N_NODES + CHUNK - 1) / CHUNK, 128, 0, stream>>>(hA, gb, gsum, gmax, gcnt);

    // ---- readout ----
    readout_kernel<<<N_GRAPHS, 256, 0, stream>>>(gsum, gmax, gcnt, Wr1, br1, Wr2, br2, (float*)d_out);
}

// Round 6
// 347.366 us; speedup vs baseline: 4.4123x; 1.1590x over previous
//
#include <hip/hip_runtime.h>
#include <hip/hip_bf16.h>

#define N_NODES 100000
#define N_EDGES 600000
#define HID 128
#define OUT_DIM 256
#define N_GRAPHS 256
#define BN 32            // nodes per block in fused SAGE kernel
#define LDA2 132         // smA row stride in floats
#define SCAN_B 512
#define SCAN_NB ((N_NODES + SCAN_B) / SCAN_B)

typedef __attribute__((ext_vector_type(8))) __bf16 bf16x8;
typedef __attribute__((ext_vector_type(4))) float f32x4;

__device__ inline f32x4 mfma16(bf16x8 a, bf16x8 b, f32x4 c) {
    return __builtin_amdgcn_mfma_f32_16x16x32_bf16(a, b, c, 0, 0, 0);
}

__device__ inline unsigned short bf_bits(__bf16 b) {
    union { __bf16 b; unsigned short u; } x; x.b = b; return x.u;
}

// ---------------- degree count ----------------
__global__ void count_kernel(const int* __restrict__ dst, int* __restrict__ deg) {
    int e = blockIdx.x * blockDim.x + threadIdx.x;
    if (e < N_EDGES) atomicAdd(&deg[dst[e]], 1);
}

// ---------------- block-level exclusive scan ----------------
__global__ __launch_bounds__(SCAN_B) void scan1_kernel(
    const int* __restrict__ deg, int* __restrict__ part, int* __restrict__ bsum)
{
    __shared__ int s[SCAN_B];
    int t = threadIdx.x;
    int i = blockIdx.x * SCAN_B + t;
    int v = (i < N_NODES) ? deg[i] : 0;
    s[t] = v;
    __syncthreads();
    #pragma unroll
    for (int off = 1; off < SCAN_B; off <<= 1) {
        int x = (t >= off) ? s[t - off] : 0;
        __syncthreads();
        s[t] += x;
        __syncthreads();
    }
    part[i] = s[t] - v;
    if (t == SCAN_B - 1) bsum[blockIdx.x] = s[t];
}

__global__ __launch_bounds__(256) void scan2_kernel(
    const int* __restrict__ bsum, int* __restrict__ boff)
{
    __shared__ int s[256];
    int t = threadIdx.x;
    int v = (t < SCAN_NB) ? bsum[t] : 0;
    s[t] = v;
    __syncthreads();
    #pragma unroll
    for (int off = 1; off < 256; off <<= 1) {
        int x = (t >= off) ? s[t - off] : 0;
        __syncthreads();
        s[t] += x;
        __syncthreads();
    }
    if (t < SCAN_NB) boff[t] = s[t] - v;
}

__global__ __launch_bounds__(SCAN_B) void scan3_kernel(
    const int* __restrict__ part, const int* __restrict__ boff,
    const int* __restrict__ deg,
    int* __restrict__ row_ptr, int* __restrict__ cursor, float* __restrict__ invdeg)
{
    int i = blockIdx.x * SCAN_B + threadIdx.x;
    int rp = part[i] + boff[blockIdx.x];
    if (i <= N_NODES) row_ptr[i] = rp;
    if (i < N_NODES) {
        cursor[i] = rp;
        invdeg[i] = 1.0f / (float)max(deg[i], 1);
    }
}

// fill CSR; also zero the pool accumulators (needed before layer-3's fused pool)
__global__ void fill_kernel(const int* __restrict__ src, const int* __restrict__ dst,
                            int* __restrict__ cursor, int* __restrict__ csr_src,
                            float* __restrict__ gsum, float* __restrict__ gmax,
                            float* __restrict__ gcnt)
{
    int e = blockIdx.x * blockDim.x + threadIdx.x;
    if (e < N_GRAPHS * HID) { gsum[e] = 0.f; gmax[e] = 0.f; }
    if (e < N_GRAPHS) gcnt[e] = 0.f;
    if (e < N_EDGES) {
        int t = dst[e];
        int pos = atomicAdd(&cursor[t], 1);
        csr_src[pos] = src[e];
    }
}

// ---------------- weight prep: stacked [Wl;Wr] -> fragment-major bf16 hi/lo ----------------
// set = blockIdx.x>>7 selects layer; layout per set (ushort):
//   p*32768 + ks*4096 + nf*512 + lane*8 + j ; value = W[k=ks*32+(lane>>4)*8+j][c=nf*16+(lane&15)]
__global__ __launch_bounds__(256) void prep_w_all(
    const float* __restrict__ W1l, const float* __restrict__ W1r,
    const float* __restrict__ W2l, const float* __restrict__ W2r,
    const float* __restrict__ W3l, const float* __restrict__ W3r,
    unsigned short* __restrict__ wf1, unsigned short* __restrict__ wf2,
    unsigned short* __restrict__ wf3)
{
    int set = blockIdx.x >> 7;
    const float* Wl = (set == 0) ? W1l : (set == 1) ? W2l : W3l;
    const float* Wr = (set == 0) ? W1r : (set == 1) ? W2r : W3r;
    unsigned short* wf = (set == 0) ? wf1 : (set == 1) ? wf2 : wf3;

    int flat = (blockIdx.x & 127) * 256 + threadIdx.x;   // 32768 per set
    int j  = flat & 7;
    int l  = (flat >> 3) & 63;
    int nf = (flat >> 9) & 7;
    int ks = flat >> 12;
    int k = ks * 32 + ((l >> 4) << 3) + j;
    int c = nf * 16 + (l & 15);
    float v = (k < HID) ? Wl[k * HID + c] : Wr[(k - HID) * HID + c];
    __bf16 hi = (__bf16)v;
    __bf16 lo = (__bf16)(v - (float)hi);
    wf[flat]         = bf_bits(hi);
    wf[32768 + flat] = bf_bits(lo);
}

// ---------------- fused gather + split-bf16 MFMA GEMM + LayerNorm + ReLU (+pool) ----------------
template<bool LAST>
__global__ __launch_bounds__(256, 8) void sage_mfma(
    const float* __restrict__ h_in,
    const int* __restrict__ row_ptr, const int* __restrict__ csr_src,
    const float* __restrict__ invdeg,
    const unsigned short* __restrict__ wf,
    const float* __restrict__ bias, const float* __restrict__ gamma,
    const float* __restrict__ beta,
    float* __restrict__ h_out,
    const int* __restrict__ gb,
    float* __restrict__ gsum, float* __restrict__ gmax, float* __restrict__ gcnt)
{
    __shared__ float smA[BN * LDA2];         // 16.9 KB: agg means, later (LAST) post-LN values
    __shared__ float lnred[BN][4][2];
    __shared__ int gbs[BN];

    const int tid  = threadIdx.x;
    const int lane = tid & 63;
    const int w    = tid >> 6;
    const int lq   = lane & 15;
    const int lg   = lane >> 4;
    const int node0 = blockIdx.x * BN;

    if (LAST && tid < BN) gbs[tid] = gb[node0 + tid];

    // ---- gather neighbor mean into smA[n][0..127] ----
    // half-wave per node: 32 lanes x f32x4 = full 512B row per edge.
    // All 4 nodes' index chains hoisted up front -> 4 independent chains in flight.
    {
        const int hw = tid >> 5;             // half-wave id, 0..7
        const int hl = lane & 31;
        const int d0 = hl * 4;

        int r0a[4], dga[4], idxa[4];
        float inva[4];
        #pragma unroll
        for (int i = 0; i < 4; ++i) {
            int node = node0 + hw * 4 + i;
            int rp0 = row_ptr[node];
            int rp1 = row_ptr[node + 1];
            r0a[i] = rp0;
            dga[i] = rp1 - rp0;
            idxa[i] = csr_src[min(rp0 + hl, N_EDGES - 1)];
            inva[i] = invdeg[node];
        }

        #pragma unroll
        for (int i = 0; i < 4; ++i) {
            int n = hw * 4 + i;
            int deg = dga[i];
            int dc = min(deg, 32);
            f32x4 a0 = {0.f, 0.f, 0.f, 0.f}, a1 = a0, a2 = a0, a3 = a0;
            int s = 0;
            for (; s + 3 < dc; s += 4) {     // 4 independent loads per step
                int i0 = __shfl(idxa[i], s,     32);
                int i1 = __shfl(idxa[i], s + 1, 32);
                int i2 = __shfl(idxa[i], s + 2, 32);
                int i3 = __shfl(idxa[i], s + 3, 32);
                a0 += *(const f32x4*)(h_in + (size_t)i0 * HID + d0);
                a1 += *(const f32x4*)(h_in + (size_t)i1 * HID + d0);
                a2 += *(const f32x4*)(h_in + (size_t)i2 * HID + d0);
                a3 += *(const f32x4*)(h_in + (size_t)i3 * HID + d0);
            }
            if (s < dc) {                     // tail 1..3, rotating accumulators
                int i0 = __shfl(idxa[i], s, 32);
                a0 += *(const f32x4*)(h_in + (size_t)i0 * HID + d0);
                if (s + 1 < dc) {
                    int i1 = __shfl(idxa[i], s + 1, 32);
                    a1 += *(const f32x4*)(h_in + (size_t)i1 * HID + d0);
                }
                if (s + 2 < dc) {
                    int i2 = __shfl(idxa[i], s + 2, 32);
                    a2 += *(const f32x4*)(h_in + (size_t)i2 * HID + d0);
                }
            }
            for (int t2 = 32; t2 < deg; ++t2) {   // P(deg>32) ~ 1e-12
                int i0 = csr_src[r0a[i] + t2];
                a0 += *(const f32x4*)(h_in + (size_t)i0 * HID + d0);
            }
            f32x4 a = (a0 + a1) + (a2 + a3);
            a *= inva[i];
            *(f32x4*)&smA[n * LDA2 + d0] = a;
        }
    }
    __syncthreads();

    // ---- split-bf16 MFMA GEMM: out[32 x 128] = [agg|root][32 x 256] @ W[256 x 128] ----
    const int nf0 = w * 2;
    const int col0 = nf0 * 16 + lq;          // = w*32 + lq
    const int col1 = col0 + 16;

    f32x4 acc[2][2];
    {
        float b0 = bias[col0], b1 = bias[col1];
        #pragma unroll
        for (int m = 0; m < 2; ++m) {
            acc[m][0] = (f32x4){b0, b0, b0, b0};
            acc[m][1] = (f32x4){b1, b1, b1, b1};
        }
    }

    const bf16x8* wfv = (const bf16x8*)wf;
    #pragma unroll 2
    for (int ks = 0; ks < 8; ++ks) {
        int base = (ks << 9) + nf0 * 64 + lane;      // ushort8 units
        bf16x8 bh0 = wfv[base];
        bf16x8 bh1 = wfv[base + 64];
        bf16x8 bl0 = wfv[base + 4096];
        bf16x8 bl1 = wfv[base + 4096 + 64];
        #pragma unroll
        for (int m = 0; m < 2; ++m) {
            float4 a0, a1;
            if (ks < 4) {
                const float* ap = &smA[(m * 16 + lq) * LDA2 + (ks << 5) + (lg << 3)];
                a0 = *(const float4*)ap;
                a1 = *(const float4*)(ap + 4);
            } else {
                const float* rp = h_in + (size_t)(node0 + m * 16 + lq) * HID
                                + ((ks - 4) << 5) + (lg << 3);
                a0 = *(const float4*)rp;
                a1 = *(const float4*)(rp + 4);
            }
            float av[8] = {a0.x, a0.y, a0.z, a0.w, a1.x, a1.y, a1.z, a1.w};
            bf16x8 ahi, alo;
            #pragma unroll
            for (int j = 0; j < 8; ++j) {
                __bf16 h = (__bf16)av[j];
                ahi[j] = h;
                alo[j] = (__bf16)(av[j] - (float)h);
            }
            acc[m][0] = mfma16(ahi, bh0, acc[m][0]);
            acc[m][0] = mfma16(alo, bh0, acc[m][0]);
            acc[m][0] = mfma16(ahi, bl0, acc[m][0]);
            acc[m][1] = mfma16(ahi, bh1, acc[m][1]);
            acc[m][1] = mfma16(alo, bh1, acc[m][1]);
            acc[m][1] = mfma16(ahi, bl1, acc[m][1]);
        }
    }

    // ---- LayerNorm partials: value (m, r) sits at node m*16+lg*4+r ----
    #pragma unroll
    for (int m = 0; m < 2; ++m) {
        #pragma unroll
        for (int r = 0; r < 4; ++r) {
            float pv = acc[m][0][r] + acc[m][1][r];
            float qv = acc[m][0][r] * acc[m][0][r] + acc[m][1][r] * acc[m][1][r];
            #pragma unroll
            for (int off = 8; off >= 1; off >>= 1) {
                pv += __shfl_xor(pv, off, 64);
                qv += __shfl_xor(qv, off, 64);
            }
            if (lq == 0) {
                int n = m * 16 + lg * 4 + r;
                lnred[n][w][0] = pv;
                lnred[n][w][1] = qv;
            }
        }
    }
    __syncthreads();   // also guarantees all smA (agg) reads are done

    // ---- finalize LN + ReLU; store to global (layers 1,2) or LDS (layer 3) ----
    float g0 = gamma[col0], g1 = gamma[col1];
    float be0 = beta[col0], be1 = beta[col1];
    #pragma unroll
    for (int m = 0; m < 2; ++m) {
        #pragma unroll
        for (int r = 0; r < 4; ++r) {
            int n = m * 16 + lg * 4 + r;
            float p = lnred[n][0][0] + lnred[n][1][0] + lnred[n][2][0] + lnred[n][3][0];
            float q = lnred[n][0][1] + lnred[n][1][1] + lnred[n][2][1] + lnred[n][3][1];
            float mu  = p * (1.0f / HID);
            float var = q * (1.0f / HID) - mu * mu;
            float rs = rsqrtf(var + 1e-5f);
            float o0 = fmaxf((acc[m][0][r] - mu) * rs * g0 + be0, 0.f);
            float o1 = fmaxf((acc[m][1][r] - mu) * rs * g1 + be1, 0.f);
            if (LAST) {
                smA[n * LDA2 + col0] = o0;
                smA[n * LDA2 + col1] = o1;
            } else {
                int node = node0 + n;
                h_out[(size_t)node * HID + col0] = o0;
                h_out[(size_t)node * HID + col1] = o1;
            }
        }
    }

    if (LAST) {
        __syncthreads();
        // block-level segmented mean/max pool over the 32 sorted nodes
        int colp = tid & 127;
        int nst = (tid >> 7) * 16, nen = nst + 16;
        int curg = gbs[nst];
        float s = 0.f, mx = 0.f;
        int c = 0;
        for (int n2 = nst; n2 < nen; ++n2) {
            int g = gbs[n2];
            if (g != curg) {
                atomicAdd(&gsum[curg * HID + colp], s);
                atomicMax((int*)&gmax[curg * HID + colp], __float_as_int(mx));
                if (colp == 0) atomicAdd(&gcnt[curg], (float)c);
                curg = g; s = 0.f; mx = 0.f; c = 0;
            }
            float v = smA[n2 * LDA2 + colp];
            s += v;
            mx = fmaxf(mx, v);   // post-ReLU: v >= 0, init 0 safe
            ++c;
        }
        atomicAdd(&gsum[curg * HID + colp], s);
        atomicMax((int*)&gmax[curg * HID + colp], __float_as_int(mx));
        if (colp == 0) atomicAdd(&gcnt[curg], (float)c);
    }
}

// ---------------- readout MLP + L2 normalize ----------------
__global__ __launch_bounds__(256) void readout_kernel(
    const float* __restrict__ gsum, const float* __restrict__ gmax,
    const float* __restrict__ gcnt,
    const float* __restrict__ Wr1, const float* __restrict__ br1,
    const float* __restrict__ Wr2, const float* __restrict__ br2,
    float* __restrict__ out)
{
    __shared__ float pooled[2 * HID];
    __shared__ float hid[HID];
    __shared__ float red[4];

    int g = blockIdx.x, tid = threadIdx.x;

    if (tid < HID) {
        float n = fmaxf(gcnt[g], 1.0f);
        pooled[tid] = gsum[g * HID + tid] / n;
    } else {
        pooled[tid] = gmax[g * HID + (tid - HID)];
    }
    __syncthreads();

    if (tid < HID) {
        float a = br1[tid];
        for (int k = 0; k < 2 * HID; ++k)
            a += pooled[k] * Wr1[k * HID + tid];
        hid[tid] = fmaxf(a, 0.0f);
    }
    __syncthreads();

    float a = br2[tid];
    for (int k = 0; k < HID; ++k)
        a += hid[k] * Wr2[k * OUT_DIM + tid];

    float ss = a * a;
    #pragma unroll
    for (int off = 32; off >= 1; off >>= 1) ss += __shfl_xor(ss, off, 64);
    int wv = tid >> 6, lane = tid & 63;
    if (lane == 0) red[wv] = ss;
    __syncthreads();
    float tot = red[0] + red[1] + red[2] + red[3];
    float nrm = fmaxf(sqrtf(tot), 1e-12f);
    out[g * OUT_DIM + tid] = a / nrm;
}

extern "C" void kernel_launch(void* const* d_in, const int* in_sizes, int n_in,
                              void* d_out, int out_size, void* d_ws, size_t ws_size,
                              hipStream_t stream) {
    const float* x   = (const float*)d_in[0];
    const int*   ei  = (const int*)d_in[1];
    const int*   gb  = (const int*)d_in[2];
    const float* W1l = (const float*)d_in[3];
    const float* W1r = (const float*)d_in[4];
    const float* b1  = (const float*)d_in[5];
    const float* g1  = (const float*)d_in[6];
    const float* be1 = (const float*)d_in[7];
    const float* W2l = (const float*)d_in[8];
    const float* W2r = (const float*)d_in[9];
    const float* b2  = (const float*)d_in[10];
    const float* g2  = (const float*)d_in[11];
    const float* be2 = (const float*)d_in[12];
    const float* W3l = (const float*)d_in[13];
    const float* W3r = (const float*)d_in[14];
    const float* b3  = (const float*)d_in[15];
    const float* g3  = (const float*)d_in[16];
    const float* be3 = (const float*)d_in[17];
    const float* Wr1 = (const float*)d_in[18];
    const float* br1 = (const float*)d_in[19];
    const float* Wr2 = (const float*)d_in[20];
    const float* br2 = (const float*)d_in[21];

    const int* src = ei;
    const int* dst = ei + N_EDGES;

    char* ws = (char*)d_ws;
    size_t off = 0;
    auto alloc = [&](size_t bytes) -> void* {
        void* p = ws + off;
        off += (bytes + 255) & ~(size_t)255;
        return p;
    };
    float* hA      = (float*)alloc((size_t)N_NODES * HID * 4);
    float* hB      = (float*)alloc((size_t)N_NODES * HID * 4);
    int*   deg     = (int*)alloc((size_t)N_NODES * 4);
    int*   part    = (int*)alloc((size_t)SCAN_NB * SCAN_B * 4);
    int*   bsum    = (int*)alloc((size_t)SCAN_NB * 4);
    int*   boff    = (int*)alloc((size_t)SCAN_NB * 4);
    int*   row_ptr = (int*)alloc((size_t)(N_NODES + 1) * 4);
    int*   cursor  = (int*)alloc((size_t)N_NODES * 4);
    float* invdeg  = (float*)alloc((size_t)N_NODES * 4);
    int*   csr_src = (int*)alloc((size_t)N_EDGES * 4);
    float* gsum    = (float*)alloc((size_t)N_GRAPHS * HID * 4);
    float* gmax    = (float*)alloc((size_t)N_GRAPHS * HID * 4);
    float* gcnt    = (float*)alloc((size_t)N_GRAPHS * 4);
    unsigned short* wf1 = (unsigned short*)alloc(65536 * 2);
    unsigned short* wf2 = (unsigned short*)alloc(65536 * 2);
    unsigned short* wf3 = (unsigned short*)alloc(65536 * 2);

    // ---- build CSR (once) + weight prep + pool-buffer zeroing ----
    hipMemsetAsync(deg, 0, (size_t)N_NODES * 4, stream);
    count_kernel<<<(N_EDGES + 255) / 256, 256, 0, stream>>>(dst, deg);
    scan1_kernel<<<SCAN_NB, SCAN_B, 0, stream>>>(deg, part, bsum);
    scan2_kernel<<<1, 256, 0, stream>>>(bsum, boff);
    scan3_kernel<<<SCAN_NB, SCAN_B, 0, stream>>>(part, boff, deg, row_ptr, cursor, invdeg);
    fill_kernel<<<(N_EDGES + 255) / 256, 256, 0, stream>>>(src, dst, cursor, csr_src,
                                                           gsum, gmax, gcnt);
    prep_w_all<<<384, 256, 0, stream>>>(W1l, W1r, W2l, W2r, W3l, W3r, wf1, wf2, wf3);

    const int sage_blocks = N_NODES / BN;   // 3125, exact

    // ---- 3 fused SAGE layers (layer 3 fuses the pool) ----
    sage_mfma<false><<<sage_blocks, 256, 0, stream>>>(x,  row_ptr, csr_src, invdeg, wf1,
                                                      b1, g1, be1, hA, gb, gsum, gmax, gcnt);
    sage_mfma<false><<<sage_blocks, 256, 0, stream>>>(hA, row_ptr, csr_src, invdeg, wf2,
                                                      b2, g2, be2, hB, gb, gsum, gmax, gcnt);
    sage_mfma<true><<<sage_blocks, 256, 0, stream>>>(hB, row_ptr, csr_src, invdeg, wf3,
                                                     b3, g3, be3, hA, gb, gsum, gmax, gcnt);

    // ---- readout ----
    readout_kernel<<<N_GRAPHS, 256, 0, stream>>>(gsum, gmax, gcnt, Wr1, br1, Wr2, br2, (float*)d_out);
}